// Round 8
// baseline (332.989 us; speedup 1.0000x reference)
//
#include <hip/hip_runtime.h>
#include <hip/hip_bf16.h>
#include <hip/hip_cooperative_groups.h>

namespace cg = cooperative_groups;

#define N_NODES 100000
#define N_EDGES 1600000
#define D 128
#define N_TILES 6250             // N_NODES/16
#define NB 512                   // buckets
#define RPB 196                  // rows per bucket (512*196 = 100352 >= N_NODES)
#define BCAP 3584                // slab capacity: mean 3136 + 8 sigma
#define MG_BLKS 512              // mega grid: 2 blocks/CU co-resident
#define MG_EDGES 3125            // edges per mega block (512*3125 = 1.6M exact)
#define SB_BLKS 256              // fallback scatterB blocks
#define SB_EDGES 6250

typedef __bf16 bf16x8 __attribute__((ext_vector_type(8)));
typedef float  f32x4  __attribute__((ext_vector_type(4)));
typedef float  f32x2  __attribute__((ext_vector_type(2)));
typedef int    i32x2  __attribute__((ext_vector_type(2)));

__device__ __forceinline__ f32x2 bf2f(unsigned u) {
    f32x2 r;
    r[0] = __int_as_float(u << 16);
    r[1] = __int_as_float(u & 0xffff0000u);
    return r;
}

// ================= MEGA: 1 cooperative launch, 3 phases =================
// P1: per-block LDS counting sort of 3125 edges (+ WT convert, bucketCnt zero)
// sync; P2: drain to svcA (far atomics) then MFMA gemm (tile = global wave)
// sync; P3: per-bucket sortsum (block b = bucket b), exact R1-proven body.
__global__ __launch_bounds__(1024, 8) void mega_kernel(
        const float* __restrict__ x, const float* __restrict__ W,
        const float* __restrict__ vals, const int* __restrict__ rows,
        const int* __restrict__ cols, float* __restrict__ out,
        __bf16* __restrict__ h, __bf16* __restrict__ WT,
        int* __restrict__ bucketCnt, i32x2* __restrict__ svcA) {
    __shared__ __align__(16) char smem[73728];   // max(P1 31KB, P2 73.7KB, P3 31.7KB)
    const int tid = threadIdx.x;
    const int bid = blockIdx.x;
    cg::grid_group grid = cg::this_grid();

    // ---------------- P1: local counting sort ----------------
    {
        i32x2* lbuf  = (i32x2*)smem;                    // 3125 recs, 25000 B
        int* lhist   = (int*)(smem + 25000);            // 512 ints
        int* sstart  = (int*)(smem + 27048);            // 512 ints
        int* lcur    = (int*)(smem + 29096);            // 512 ints
        if (tid < NB) lhist[tid] = 0;
        __syncthreads();

        const int base = bid * MG_EDGES;
        i32x2 r0, r1, r2, r3;
        int   b0, b1, b2, b3;
#define LOADREC(K, RK, BK)                                             \
        {                                                              \
            int e = base + tid + (K) * 1024;                           \
            int rr = rows[e];                                          \
            BK = rr / RPB;                                             \
            int local = rr - BK * RPB;                                 \
            RK[0] = (local << 17) | cols[e];                           \
            RK[1] = __float_as_int(vals[e]);                           \
            atomicAdd(&lhist[BK], 1);                                  \
        }
        LOADREC(0, r0, b0) LOADREC(1, r1, b1) LOADREC(2, r2, b2)
        if (tid < MG_EDGES - 3 * 1024) { LOADREC(3, r3, b3) }
#undef LOADREC

        // WT convert (blocks 0..15) + bucketCnt zero (block 16)
        if (bid < 16) {
            int t = bid * 1024 + tid;
            int k = t >> 7, n2 = t & 127;
            WT[n2 * D + k] = (__bf16)W[t];
        }
        if (bid == 16 && tid < NB) bucketCnt[tid] = 0;
        __syncthreads();

        // single-wave scan over 512 bins: 8 consecutive bins per lane
        if (tid < 64) {
            const int bb = tid * 8;
            int run = 0;
#pragma unroll
            for (int j = 0; j < 8; ++j) run += lhist[bb + j];
            int s = run;
#pragma unroll
            for (int d = 1; d < 64; d <<= 1) {
                int t2 = __shfl_up(s, d, 64);
                if (tid >= d) s += t2;
            }
            int ex = s - run;
#pragma unroll
            for (int j = 0; j < 8; ++j) {
                sstart[bb + j] = ex;
                lcur[bb + j]   = ex;
                ex += lhist[bb + j];
            }
        }
        __syncthreads();

        // scatter into bucket-sorted lbuf
        lbuf[atomicAdd(&lcur[b0], 1)] = r0;
        lbuf[atomicAdd(&lcur[b1], 1)] = r1;
        lbuf[atomicAdd(&lcur[b2], 1)] = r2;
        if (tid < MG_EDGES - 3 * 1024) lbuf[atomicAdd(&lcur[b3], 1)] = r3;
        __syncthreads();
    }
    grid.sync();   // bucketCnt zeroed + WT ready, all lbufs sorted

    // ---------------- P2: drain + gemm ----------------
    {
        i32x2* lbuf  = (i32x2*)smem;
        int* lhist   = (int*)(smem + 25000);
        int* sstart  = (int*)(smem + 27048);
        if (tid < NB) {
            int n = lhist[tid];
            if (n > 0) {
                int g = atomicAdd(&bucketCnt[tid], n);
                int s = sstart[tid];
                for (int i = 0; i < n; ++i)
                    if (g + i < BCAP) svcA[(size_t)tid * BCAP + g + i] = lbuf[s + i];
            }
        }
        __syncthreads();   // lbuf region now free for gemm lsm

        const int wave = tid >> 6;
        const int lane = tid & 63;
        const int tile = bid * 16 + wave;   // global wave id = tile
        if (tile < N_TILES) {
            __bf16 (*lsm)[144] = (__bf16 (*)[144])(smem + wave * 4608);
            const int m = lane & 15, quad = lane >> 4;
            const float* xp = x + (size_t)(tile * 16 + m) * D + quad * 8;

            f32x4 acc[8];
#pragma unroll
            for (int ct = 0; ct < 8; ++ct) acc[ct] = (f32x4)(0.0f);
#pragma unroll
            for (int kk = 0; kk < 4; ++kk) {
                f32x4 a0 = *(const f32x4*)(xp + kk * 32);
                f32x4 a1 = *(const f32x4*)(xp + kk * 32 + 4);
                bf16x8 a;
#pragma unroll
                for (int j = 0; j < 4; ++j) { a[j] = (__bf16)a0[j]; a[j + 4] = (__bf16)a1[j]; }
#pragma unroll
                for (int ct = 0; ct < 8; ++ct) {
                    bf16x8 bfrag = *(const bf16x8*)(WT + (size_t)(ct * 16 + m) * D + kk * 32 + quad * 8);
                    acc[ct] = __builtin_amdgcn_mfma_f32_16x16x32_bf16(a, bfrag, acc[ct], 0, 0, 0);
                }
            }
#pragma unroll
            for (int ct = 0; ct < 8; ++ct)
#pragma unroll
                for (int r = 0; r < 4; ++r)
                    lsm[quad * 4 + r][ct * 16 + m] = (__bf16)acc[ct][r];
#pragma unroll
            for (int i = 0; i < 4; ++i) {
                int rl = i * 4 + quad;
                bf16x8 vv = *(const bf16x8*)&lsm[rl][m * 8];
                *(bf16x8*)(h + (size_t)(tile * 16 + rl) * D + m * 8) = vv;
            }
        }
    }
    grid.sync();   // h + svcA + bucketCnt complete

    // ---------------- P3: sortsum (block b = bucket b) ----------------
    {
        i32x2* lbuf = (i32x2*)smem;                    // 3584 recs, 28672 B
        int* lhist  = (int*)(smem + 28672);
        int* send   = (int*)(smem + 29696);
        int* lcur   = (int*)(smem + 30720);
        const int b = bid;
        const int n = min(bucketCnt[b], BCAP);
        const i32x2* win = svcA + (size_t)b * BCAP;

        if (tid < 256) lhist[tid] = 0;
        __syncthreads();

        i32x2 rec0, rec1, rec2, rec3;
        const int i0 = tid, i1 = tid + 1024, i2 = tid + 2048, i3 = tid + 3072;
        if (i0 < n) { rec0 = win[i0]; atomicAdd(&lhist[((unsigned)rec0[0]) >> 17], 1); }
        if (i1 < n) { rec1 = win[i1]; atomicAdd(&lhist[((unsigned)rec1[0]) >> 17], 1); }
        if (i2 < n) { rec2 = win[i2]; atomicAdd(&lhist[((unsigned)rec2[0]) >> 17], 1); }
        if (i3 < n) { rec3 = win[i3]; atomicAdd(&lhist[((unsigned)rec3[0]) >> 17], 1); }
        __syncthreads();

        if (tid < 64) {
            int b0 = lhist[tid * 4 + 0], b1 = lhist[tid * 4 + 1];
            int b2 = lhist[tid * 4 + 2], b3 = lhist[tid * 4 + 3];
            int p0 = b0, p1 = p0 + b1, p2 = p1 + b2, p3 = p2 + b3;
            int s = p3;
#pragma unroll
            for (int d = 1; d < 64; d <<= 1) {
                int t2 = __shfl_up(s, d, 64);
                if (tid >= d) s += t2;
            }
            int ex = s - p3;
            send[tid * 4 + 0] = ex + p0;
            send[tid * 4 + 1] = ex + p1;
            send[tid * 4 + 2] = ex + p2;
            send[tid * 4 + 3] = ex + p3;
            lcur[tid * 4 + 0] = ex;
            lcur[tid * 4 + 1] = ex + p0;
            lcur[tid * 4 + 2] = ex + p1;
            lcur[tid * 4 + 3] = ex + p2;
        }
        __syncthreads();

        if (i0 < n) { int rl = ((unsigned)rec0[0]) >> 17; lbuf[atomicAdd(&lcur[rl], 1)] = rec0; }
        if (i1 < n) { int rl = ((unsigned)rec1[0]) >> 17; lbuf[atomicAdd(&lcur[rl], 1)] = rec1; }
        if (i2 < n) { int rl = ((unsigned)rec2[0]) >> 17; lbuf[atomicAdd(&lcur[rl], 1)] = rec2; }
        if (i3 < n) { int rl = ((unsigned)rec3[0]) >> 17; lbuf[atomicAdd(&lcur[rl], 1)] = rec3; }
        __syncthreads();

        const int wave = tid >> 6;
        const int lane = tid & 63;
        const char* hb = (const char*)h;
        const unsigned lo4 = (unsigned)lane * 4u;
        for (int rl = wave; rl < RPB; rl += 16) {
            int gr = b * RPB + rl;
            if (gr >= N_NODES) break;
            int s = rl ? send[rl - 1] : 0;
            int e = send[rl];

            f32x2 acc0 = (f32x2)(0.0f), acc1 = (f32x2)(0.0f);
            f32x2 acc2 = (f32x2)(0.0f), acc3 = (f32x2)(0.0f);
            int i = s;
            for (; i + 7 < e; i += 8) {
                i32x2 r0 = lbuf[i],     r1 = lbuf[i + 1], r2 = lbuf[i + 2], r3 = lbuf[i + 3];
                i32x2 r4 = lbuf[i + 4], r5 = lbuf[i + 5], r6 = lbuf[i + 6], r7 = lbuf[i + 7];
                unsigned o0 = (((unsigned)r0[0] & 0x1FFFFu) << 8) + lo4;
                unsigned o1 = (((unsigned)r1[0] & 0x1FFFFu) << 8) + lo4;
                unsigned o2 = (((unsigned)r2[0] & 0x1FFFFu) << 8) + lo4;
                unsigned o3 = (((unsigned)r3[0] & 0x1FFFFu) << 8) + lo4;
                unsigned o4 = (((unsigned)r4[0] & 0x1FFFFu) << 8) + lo4;
                unsigned o5 = (((unsigned)r5[0] & 0x1FFFFu) << 8) + lo4;
                unsigned o6 = (((unsigned)r6[0] & 0x1FFFFu) << 8) + lo4;
                unsigned o7 = (((unsigned)r7[0] & 0x1FFFFu) << 8) + lo4;
                unsigned u0 = *(const unsigned*)(hb + o0);
                unsigned u1 = *(const unsigned*)(hb + o1);
                unsigned u2 = *(const unsigned*)(hb + o2);
                unsigned u3 = *(const unsigned*)(hb + o3);
                unsigned u4 = *(const unsigned*)(hb + o4);
                unsigned u5 = *(const unsigned*)(hb + o5);
                unsigned u6 = *(const unsigned*)(hb + o6);
                unsigned u7 = *(const unsigned*)(hb + o7);
                acc0 += bf2f(u0) * __int_as_float(r0[1]);
                acc1 += bf2f(u1) * __int_as_float(r1[1]);
                acc2 += bf2f(u2) * __int_as_float(r2[1]);
                acc3 += bf2f(u3) * __int_as_float(r3[1]);
                acc0 += bf2f(u4) * __int_as_float(r4[1]);
                acc1 += bf2f(u5) * __int_as_float(r5[1]);
                acc2 += bf2f(u6) * __int_as_float(r6[1]);
                acc3 += bf2f(u7) * __int_as_float(r7[1]);
            }
            for (; i + 3 < e; i += 4) {
                i32x2 r0 = lbuf[i], r1 = lbuf[i + 1], r2 = lbuf[i + 2], r3 = lbuf[i + 3];
                unsigned o0 = (((unsigned)r0[0] & 0x1FFFFu) << 8) + lo4;
                unsigned o1 = (((unsigned)r1[0] & 0x1FFFFu) << 8) + lo4;
                unsigned o2 = (((unsigned)r2[0] & 0x1FFFFu) << 8) + lo4;
                unsigned o3 = (((unsigned)r3[0] & 0x1FFFFu) << 8) + lo4;
                unsigned u0 = *(const unsigned*)(hb + o0);
                unsigned u1 = *(const unsigned*)(hb + o1);
                unsigned u2 = *(const unsigned*)(hb + o2);
                unsigned u3 = *(const unsigned*)(hb + o3);
                acc0 += bf2f(u0) * __int_as_float(r0[1]);
                acc1 += bf2f(u1) * __int_as_float(r1[1]);
                acc2 += bf2f(u2) * __int_as_float(r2[1]);
                acc3 += bf2f(u3) * __int_as_float(r3[1]);
            }
            for (; i < e; ++i) {
                i32x2 r0 = lbuf[i];
                unsigned o0 = (((unsigned)r0[0] & 0x1FFFFu) << 8) + lo4;
                unsigned u0 = *(const unsigned*)(hb + o0);
                acc0 += bf2f(u0) * __int_as_float(r0[1]);
            }

            f32x2 t01 = acc0 + acc1, t23 = acc2 + acc3;
            f32x2 tt = t01 + t23;
            f32x2 o;
            o[0] = fmaxf(tt[0], 0.0f);
            o[1] = fmaxf(tt[1], 0.0f);
            __builtin_nontemporal_store(o, (f32x2*)(out + (size_t)gr * D + lane * 2));
        }
    }
}

// ================= FALLBACK: proven R7 4-kernel path =================
__global__ __launch_bounds__(256) void prep_kernel(const float* __restrict__ W,
                                                   __bf16* __restrict__ WT,
                                                   int* __restrict__ bucketCnt) {
    int t = blockIdx.x * 256 + threadIdx.x;
    int k = t >> 7, n = t & 127;
    WT[n * D + k] = (__bf16)W[t];
    if (t < NB) bucketCnt[t] = 0;
}

__global__ __launch_bounds__(256) void gemm_kernel(
        const float* __restrict__ x,
        const __bf16* __restrict__ WT,
        __bf16* __restrict__ h) {
    __shared__ __bf16 lsm[4][16][144];
    const int wave = threadIdx.x >> 6;
    const int lane = threadIdx.x & 63;
    const int tile = blockIdx.x * 4 + wave;
    if (tile >= N_TILES) return;
    const int m = lane & 15, quad = lane >> 4;
    const float* xp = x + (size_t)(tile * 16 + m) * D + quad * 8;

    f32x4 acc[8];
#pragma unroll
    for (int ct = 0; ct < 8; ++ct) acc[ct] = (f32x4)(0.0f);
#pragma unroll
    for (int kk = 0; kk < 4; ++kk) {
        f32x4 a0 = *(const f32x4*)(xp + kk * 32);
        f32x4 a1 = *(const f32x4*)(xp + kk * 32 + 4);
        bf16x8 a;
#pragma unroll
        for (int j = 0; j < 4; ++j) { a[j] = (__bf16)a0[j]; a[j + 4] = (__bf16)a1[j]; }
#pragma unroll
        for (int ct = 0; ct < 8; ++ct) {
            bf16x8 b = *(const bf16x8*)(WT + (size_t)(ct * 16 + m) * D + kk * 32 + quad * 8);
            acc[ct] = __builtin_amdgcn_mfma_f32_16x16x32_bf16(a, b, acc[ct], 0, 0, 0);
        }
    }
#pragma unroll
    for (int ct = 0; ct < 8; ++ct)
#pragma unroll
        for (int r = 0; r < 4; ++r)
            lsm[wave][quad * 4 + r][ct * 16 + m] = (__bf16)acc[ct][r];
#pragma unroll
    for (int i = 0; i < 4; ++i) {
        int rl = i * 4 + quad;
        bf16x8 vv = *(const bf16x8*)&lsm[wave][rl][m * 8];
        *(bf16x8*)(h + (size_t)(tile * 16 + rl) * D + m * 8) = vv;
    }
}

__global__ __launch_bounds__(1024, 8) void scatterB_kernel(
        const int* __restrict__ rows, const int* __restrict__ cols,
        const float* __restrict__ vals,
        int* __restrict__ bucketCnt, i32x2* __restrict__ svcA) {
    __shared__ i32x2 lbuf[SB_EDGES];
    __shared__ int   lhist[NB];
    __shared__ int   sstart[NB];
    __shared__ int   lcur[NB];
    const int tid  = threadIdx.x;
    const int base = blockIdx.x * SB_EDGES;

    if (tid < NB) lhist[tid] = 0;
    __syncthreads();

    i32x2 r0, r1, r2, r3, r4, r5, r6;
    int   b0, b1, b2, b3, b4, b5, b6;
#define LOADREC(K, RK, BK)                                             \
    {                                                                  \
        int e = base + tid + (K) * 1024;                               \
        int rr = rows[e];                                              \
        BK = rr / RPB;                                                 \
        int local = rr - BK * RPB;                                     \
        RK[0] = (local << 17) | cols[e];                               \
        RK[1] = __float_as_int(vals[e]);                               \
        atomicAdd(&lhist[BK], 1);                                      \
    }
    LOADREC(0, r0, b0) LOADREC(1, r1, b1) LOADREC(2, r2, b2)
    LOADREC(3, r3, b3) LOADREC(4, r4, b4) LOADREC(5, r5, b5)
    if (tid < SB_EDGES - 6 * 1024) { LOADREC(6, r6, b6) }
#undef LOADREC
    __syncthreads();

    if (tid < 64) {
        const int bb = tid * 8;
        int run = 0;
#pragma unroll
        for (int j = 0; j < 8; ++j) run += lhist[bb + j];
        int s = run;
#pragma unroll
        for (int d = 1; d < 64; d <<= 1) {
            int t2 = __shfl_up(s, d, 64);
            if (tid >= d) s += t2;
        }
        int ex = s - run;
#pragma unroll
        for (int j = 0; j < 8; ++j) {
            sstart[bb + j] = ex;
            lcur[bb + j]   = ex;
            ex += lhist[bb + j];
        }
    }
    __syncthreads();

    lbuf[atomicAdd(&lcur[b0], 1)] = r0;
    lbuf[atomicAdd(&lcur[b1], 1)] = r1;
    lbuf[atomicAdd(&lcur[b2], 1)] = r2;
    lbuf[atomicAdd(&lcur[b3], 1)] = r3;
    lbuf[atomicAdd(&lcur[b4], 1)] = r4;
    lbuf[atomicAdd(&lcur[b5], 1)] = r5;
    if (tid < SB_EDGES - 6 * 1024) lbuf[atomicAdd(&lcur[b6], 1)] = r6;
    __syncthreads();

    if (tid < NB) {
        int n = lhist[tid];
        if (n > 0) {
            int g = atomicAdd(&bucketCnt[tid], n);
            int s = sstart[tid];
            for (int i = 0; i < n; ++i)
                if (g + i < BCAP) svcA[(size_t)tid * BCAP + g + i] = lbuf[s + i];
        }
    }
}

__global__ __launch_bounds__(1024, 8) void sortsum_kernel(
        const __bf16* __restrict__ h, const int* __restrict__ bucketCnt,
        const i32x2* __restrict__ svcA, float* __restrict__ out) {
    __shared__ i32x2 lbuf[BCAP];
    __shared__ int   lhist[256];
    __shared__ int   send[256];
    __shared__ int   lcur[256];
    const int b   = blockIdx.x;
    const int tid = threadIdx.x;
    const int n   = min(bucketCnt[b], BCAP);
    const i32x2* win = svcA + (size_t)b * BCAP;

    if (tid < 256) lhist[tid] = 0;
    __syncthreads();

    i32x2 rec0, rec1, rec2, rec3;
    const int i0 = tid, i1 = tid + 1024, i2 = tid + 2048, i3 = tid + 3072;
    if (i0 < n) { rec0 = win[i0]; atomicAdd(&lhist[((unsigned)rec0[0]) >> 17], 1); }
    if (i1 < n) { rec1 = win[i1]; atomicAdd(&lhist[((unsigned)rec1[0]) >> 17], 1); }
    if (i2 < n) { rec2 = win[i2]; atomicAdd(&lhist[((unsigned)rec2[0]) >> 17], 1); }
    if (i3 < n) { rec3 = win[i3]; atomicAdd(&lhist[((unsigned)rec3[0]) >> 17], 1); }
    __syncthreads();

    if (tid < 64) {
        int b0 = lhist[tid * 4 + 0], b1 = lhist[tid * 4 + 1];
        int b2 = lhist[tid * 4 + 2], b3 = lhist[tid * 4 + 3];
        int p0 = b0, p1 = p0 + b1, p2 = p1 + b2, p3 = p2 + b3;
        int s = p3;
#pragma unroll
        for (int d = 1; d < 64; d <<= 1) {
            int t2 = __shfl_up(s, d, 64);
            if (tid >= d) s += t2;
        }
        int ex = s - p3;
        send[tid * 4 + 0] = ex + p0;
        send[tid * 4 + 1] = ex + p1;
        send[tid * 4 + 2] = ex + p2;
        send[tid * 4 + 3] = ex + p3;
        lcur[tid * 4 + 0] = ex;
        lcur[tid * 4 + 1] = ex + p0;
        lcur[tid * 4 + 2] = ex + p1;
        lcur[tid * 4 + 3] = ex + p2;
    }
    __syncthreads();

    if (i0 < n) { int rl = ((unsigned)rec0[0]) >> 17; lbuf[atomicAdd(&lcur[rl], 1)] = rec0; }
    if (i1 < n) { int rl = ((unsigned)rec1[0]) >> 17; lbuf[atomicAdd(&lcur[rl], 1)] = rec1; }
    if (i2 < n) { int rl = ((unsigned)rec2[0]) >> 17; lbuf[atomicAdd(&lcur[rl], 1)] = rec2; }
    if (i3 < n) { int rl = ((unsigned)rec3[0]) >> 17; lbuf[atomicAdd(&lcur[rl], 1)] = rec3; }
    __syncthreads();

    const int wave = tid >> 6;
    const int lane = tid & 63;
    const char* hb = (const char*)h;
    const unsigned lo4 = (unsigned)lane * 4u;
    for (int rl = wave; rl < RPB; rl += 16) {
        int gr = b * RPB + rl;
        if (gr >= N_NODES) break;
        int s = rl ? send[rl - 1] : 0;
        int e = send[rl];

        f32x2 acc0 = (f32x2)(0.0f), acc1 = (f32x2)(0.0f);
        f32x2 acc2 = (f32x2)(0.0f), acc3 = (f32x2)(0.0f);
        int i = s;
        for (; i + 7 < e; i += 8) {
            i32x2 r0 = lbuf[i],     r1 = lbuf[i + 1], r2 = lbuf[i + 2], r3 = lbuf[i + 3];
            i32x2 r4 = lbuf[i + 4], r5 = lbuf[i + 5], r6 = lbuf[i + 6], r7 = lbuf[i + 7];
            unsigned o0 = (((unsigned)r0[0] & 0x1FFFFu) << 8) + lo4;
            unsigned o1 = (((unsigned)r1[0] & 0x1FFFFu) << 8) + lo4;
            unsigned o2 = (((unsigned)r2[0] & 0x1FFFFu) << 8) + lo4;
            unsigned o3 = (((unsigned)r3[0] & 0x1FFFFu) << 8) + lo4;
            unsigned o4 = (((unsigned)r4[0] & 0x1FFFFu) << 8) + lo4;
            unsigned o5 = (((unsigned)r5[0] & 0x1FFFFu) << 8) + lo4;
            unsigned o6 = (((unsigned)r6[0] & 0x1FFFFu) << 8) + lo4;
            unsigned o7 = (((unsigned)r7[0] & 0x1FFFFu) << 8) + lo4;
            unsigned u0 = *(const unsigned*)(hb + o0);
            unsigned u1 = *(const unsigned*)(hb + o1);
            unsigned u2 = *(const unsigned*)(hb + o2);
            unsigned u3 = *(const unsigned*)(hb + o3);
            unsigned u4 = *(const unsigned*)(hb + o4);
            unsigned u5 = *(const unsigned*)(hb + o5);
            unsigned u6 = *(const unsigned*)(hb + o6);
            unsigned u7 = *(const unsigned*)(hb + o7);
            acc0 += bf2f(u0) * __int_as_float(r0[1]);
            acc1 += bf2f(u1) * __int_as_float(r1[1]);
            acc2 += bf2f(u2) * __int_as_float(r2[1]);
            acc3 += bf2f(u3) * __int_as_float(r3[1]);
            acc0 += bf2f(u4) * __int_as_float(r4[1]);
            acc1 += bf2f(u5) * __int_as_float(r5[1]);
            acc2 += bf2f(u6) * __int_as_float(r6[1]);
            acc3 += bf2f(u7) * __int_as_float(r7[1]);
        }
        for (; i + 3 < e; i += 4) {
            i32x2 r0 = lbuf[i], r1 = lbuf[i + 1], r2 = lbuf[i + 2], r3 = lbuf[i + 3];
            unsigned o0 = (((unsigned)r0[0] & 0x1FFFFu) << 8) + lo4;
            unsigned o1 = (((unsigned)r1[0] & 0x1FFFFu) << 8) + lo4;
            unsigned o2 = (((unsigned)r2[0] & 0x1FFFFu) << 8) + lo4;
            unsigned o3 = (((unsigned)r3[0] & 0x1FFFFu) << 8) + lo4;
            unsigned u0 = *(const unsigned*)(hb + o0);
            unsigned u1 = *(const unsigned*)(hb + o1);
            unsigned u2 = *(const unsigned*)(hb + o2);
            unsigned u3 = *(const unsigned*)(hb + o3);
            acc0 += bf2f(u0) * __int_as_float(r0[1]);
            acc1 += bf2f(u1) * __int_as_float(r1[1]);
            acc2 += bf2f(u2) * __int_as_float(r2[1]);
            acc3 += bf2f(u3) * __int_as_float(r3[1]);
        }
        for (; i < e; ++i) {
            i32x2 r0 = lbuf[i];
            unsigned o0 = (((unsigned)r0[0] & 0x1FFFFu) << 8) + lo4;
            unsigned u0 = *(const unsigned*)(hb + o0);
            acc0 += bf2f(u0) * __int_as_float(r0[1]);
        }

        f32x2 t01 = acc0 + acc1, t23 = acc2 + acc3;
        f32x2 tt = t01 + t23;
        f32x2 o;
        o[0] = fmaxf(tt[0], 0.0f);
        o[1] = fmaxf(tt[1], 0.0f);
        __builtin_nontemporal_store(o, (f32x2*)(out + (size_t)gr * D + lane * 2));
    }
}

extern "C" void kernel_launch(void* const* d_in, const int* in_sizes, int n_in,
                              void* d_out, int out_size, void* d_ws, size_t ws_size,
                              hipStream_t stream) {
    const float* x    = (const float*)d_in[0];
    const float* w    = (const float*)d_in[1];
    const float* vals = (const float*)d_in[2];
    const int*   rows = (const int*)d_in[3];
    const int*   cols = (const int*)d_in[4];
    float*       out  = (float*)d_out;

    // ---- workspace (~40.3 MB) ----
    char* p = (char*)d_ws;
    __bf16* h         = (__bf16*)p;  p += (size_t)N_NODES * D * 2;          // 25.6 MB
    __bf16* WT        = (__bf16*)p;  p += (size_t)D * D * 2;                // 32 KB
    int*    bucketCnt = (int*)p;     p += 4096;                             // NB ints
    i32x2*  svcA      = (i32x2*)p;   p += (size_t)NB * BCAP * 8;            // 14.7 MB

    void* kargs[] = {(void*)&x, (void*)&w, (void*)&vals, (void*)&rows, (void*)&cols,
                     (void*)&out, (void*)&h, (void*)&WT, (void*)&bucketCnt, (void*)&svcA};
    hipError_t err = hipLaunchCooperativeKernel((const void*)mega_kernel,
                                                dim3(MG_BLKS), dim3(1024),
                                                kargs, 0, stream);
    if (err != hipSuccess) {
        (void)hipGetLastError();   // clear error, fall back to proven 4-kernel path
        prep_kernel<<<64, 256, 0, stream>>>(w, WT, bucketCnt);
        gemm_kernel<<<(N_TILES + 3) / 4, 256, 0, stream>>>(x, WT, h);
        scatterB_kernel<<<SB_BLKS, 1024, 0, stream>>>(rows, cols, vals, bucketCnt, svcA);
        sortsum_kernel<<<NB, 1024, 0, stream>>>(h, bucketCnt, svcA, out);
    }
}

// Round 9
// 216.678 us; speedup vs baseline: 1.5368x; 1.5368x over previous
//
#include <hip/hip_runtime.h>
#include <hip/hip_bf16.h>

#define N_NODES 100000
#define N_EDGES 1600000
#define D 128
#define N_TILES 6250             // N_NODES/16
#define NB 512                   // buckets
#define RPB 196                  // rows per bucket (512*196 = 100352 >= N_NODES)
#define BCAP 3584                // slab capacity: mean 3136 + 8 sigma
#define SB_BLKS 256              // scatterB blocks: 1 per CU, zero tail
#define SB_EDGES 6250            // 256*6250 = 1.6M exact

typedef __bf16 bf16x8 __attribute__((ext_vector_type(8)));
typedef float  f32x4  __attribute__((ext_vector_type(4)));
typedef float  f32x2  __attribute__((ext_vector_type(2)));
typedef int    i32x2  __attribute__((ext_vector_type(2)));

// ---- K1: W transpose (fp32 -> bf16 WT) + zero bucket cursors ----
__global__ __launch_bounds__(256) void prep_kernel(const float* __restrict__ W,
                                                   __bf16* __restrict__ WT,
                                                   int* __restrict__ bucketCnt) {
    int t = blockIdx.x * 256 + threadIdx.x;   // 16384 threads
    int k = t >> 7, n = t & 127;
    WT[n * D + k] = (__bf16)W[t];
    if (t < NB) bucketCnt[t] = 0;
}

// ---- K2: GEMM h = bf16(x) @ bf16(W) (verified; NT x-loads: x is streamed
// once with zero reuse -> keep L2 for WT + h, which sortsum reads next) ----
__global__ __launch_bounds__(256) void gemm_kernel(
        const float* __restrict__ x,
        const __bf16* __restrict__ WT,
        __bf16* __restrict__ h) {
    __shared__ __bf16 lsm[4][16][144];
    const int wave = threadIdx.x >> 6;
    const int lane = threadIdx.x & 63;
    const int tile = blockIdx.x * 4 + wave;
    if (tile >= N_TILES) return;
    const int m = lane & 15, quad = lane >> 4;
    const float* xp = x + (size_t)(tile * 16 + m) * D + quad * 8;

    f32x4 acc[8];
#pragma unroll
    for (int ct = 0; ct < 8; ++ct) acc[ct] = (f32x4)(0.0f);
#pragma unroll
    for (int kk = 0; kk < 4; ++kk) {
        f32x4 a0 = __builtin_nontemporal_load((const f32x4*)(xp + kk * 32));
        f32x4 a1 = __builtin_nontemporal_load((const f32x4*)(xp + kk * 32 + 4));
        bf16x8 a;
#pragma unroll
        for (int j = 0; j < 4; ++j) { a[j] = (__bf16)a0[j]; a[j + 4] = (__bf16)a1[j]; }
#pragma unroll
        for (int ct = 0; ct < 8; ++ct) {
            bf16x8 b = *(const bf16x8*)(WT + (size_t)(ct * 16 + m) * D + kk * 32 + quad * 8);
            acc[ct] = __builtin_amdgcn_mfma_f32_16x16x32_bf16(a, b, acc[ct], 0, 0, 0);
        }
    }
#pragma unroll
    for (int ct = 0; ct < 8; ++ct)
#pragma unroll
        for (int r = 0; r < 4; ++r)
            lsm[wave][quad * 4 + r][ct * 16 + m] = (__bf16)acc[ct][r];
#pragma unroll
    for (int i = 0; i < 4; ++i) {
        int rl = i * 4 + quad;
        bf16x8 vv = *(const bf16x8*)&lsm[wave][rl][m * 8];
        *(bf16x8*)(h + (size_t)(tile * 16 + rl) * D + m * 8) = vv;
    }
}

// ---- K3: scatterB — exact LDS counting sort + COOPERATIVE drain ----
// 256 blocks x 1024 threads x 6250 edges. Drain now uses 2 threads/bucket
// (even thread claims the far atomic, publishes g via lcur; both copy
// interleaved halves) -> serial run 12 -> 6, all 1024 threads active,
// adjacent threads write adjacent records (16B-coalesced pairs).
__global__ __launch_bounds__(1024, 8) void scatterB_kernel(
        const int* __restrict__ rows, const int* __restrict__ cols,
        const float* __restrict__ vals,
        int* __restrict__ bucketCnt, i32x2* __restrict__ svcA) {
    __shared__ i32x2 lbuf[SB_EDGES];   // 50000 B
    __shared__ int   lhist[NB];        // counts (preserved)
    __shared__ int   sstart[NB];       // exclusive starts
    __shared__ int   lcur[NB];         // scatter cursors, then g broadcast
    const int tid  = threadIdx.x;
    const int base = blockIdx.x * SB_EDGES;

    if (tid < NB) lhist[tid] = 0;
    __syncthreads();

    // load 7 records/thread into NAMED registers + histogram
    // K=0..5 always in range (5*1024+1023 = 6143 < 6250); K=6 needs tid<106
    i32x2 r0, r1, r2, r3, r4, r5, r6;
    int   b0, b1, b2, b3, b4, b5, b6;
#define LOADREC(K, RK, BK)                                             \
    {                                                                  \
        int e = base + tid + (K) * 1024;                               \
        int rr = rows[e];                                              \
        BK = rr / RPB;                                                 \
        int local = rr - BK * RPB;                                     \
        RK[0] = (local << 17) | cols[e];                               \
        RK[1] = __float_as_int(vals[e]);                               \
        atomicAdd(&lhist[BK], 1);                                      \
    }
    LOADREC(0, r0, b0) LOADREC(1, r1, b1) LOADREC(2, r2, b2)
    LOADREC(3, r3, b3) LOADREC(4, r4, b4) LOADREC(5, r5, b5)
    if (tid < SB_EDGES - 6 * 1024) { LOADREC(6, r6, b6) }
#undef LOADREC
    __syncthreads();

    // single-wave scan over 512 bins: 8 consecutive bins per lane
    if (tid < 64) {
        const int bb = tid * 8;
        int run = 0;
#pragma unroll
        for (int j = 0; j < 8; ++j) run += lhist[bb + j];
        int s = run;
#pragma unroll
        for (int d = 1; d < 64; d <<= 1) {
            int t2 = __shfl_up(s, d, 64);
            if (tid >= d) s += t2;
        }
        int ex = s - run;              // exclusive prefix of this 8-bin group
#pragma unroll
        for (int j = 0; j < 8; ++j) {
            sstart[bb + j] = ex;
            lcur[bb + j]   = ex;
            ex += lhist[bb + j];
        }
    }
    __syncthreads();

    // scatter registers into bucket-sorted lbuf
    lbuf[atomicAdd(&lcur[b0], 1)] = r0;
    lbuf[atomicAdd(&lcur[b1], 1)] = r1;
    lbuf[atomicAdd(&lcur[b2], 1)] = r2;
    lbuf[atomicAdd(&lcur[b3], 1)] = r3;
    lbuf[atomicAdd(&lcur[b4], 1)] = r4;
    lbuf[atomicAdd(&lcur[b5], 1)] = r5;
    if (tid < SB_EDGES - 6 * 1024) lbuf[atomicAdd(&lcur[b6], 1)] = r6;
    __syncthreads();

    // drain step 1: thread t < 512 claims bucket t's global window once
    if (tid < NB) {
        int n = lhist[tid];
        if (n > 0) lcur[tid] = atomicAdd(&bucketCnt[tid], n);   // reuse lcur as g
    }
    __syncthreads();

    // drain step 2: 2 threads per bucket copy interleaved halves
    {
        const int bkt  = tid >> 1;
        const int half = tid & 1;
        int n = lhist[bkt];
        if (n > 0) {
            int g = lcur[bkt];
            int s = sstart[bkt];
            i32x2* dst = svcA + (size_t)bkt * BCAP;
            for (int i = half; i < n; i += 2)
                if (g + i < BCAP) dst[g + i] = lbuf[s + i];
        }
    }
}

// ---- K4: fused local sort (hist + single-wave shuffle scan) + segsum + relu
// EXACT R1 code (proven 64.5us, ~6.4 TB/s delivered = fabric ceiling).
__device__ __forceinline__ f32x2 bf2f(unsigned u) {
    f32x2 r;
    r[0] = __int_as_float(u << 16);
    r[1] = __int_as_float(u & 0xffff0000u);
    return r;
}

__global__ __launch_bounds__(1024, 8) void sortsum_kernel(
        const __bf16* __restrict__ h, const int* __restrict__ bucketCnt,
        const i32x2* __restrict__ svcA, float* __restrict__ out) {
    __shared__ i32x2 lbuf[BCAP];     // 28 KB
    __shared__ int   lhist[256];
    __shared__ int   send[256];      // inclusive scan (row ends)
    __shared__ int   lcur[256];      // scatter cursors (row starts, mutated)
    const int b   = blockIdx.x;
    const int tid = threadIdx.x;
    const int n   = min(bucketCnt[b], BCAP);
    const i32x2* win = svcA + (size_t)b * BCAP;

    if (tid < 256) lhist[tid] = 0;
    __syncthreads();

    // load window into registers (<=4 recs/thread) + LDS histogram
    i32x2 rec0, rec1, rec2, rec3;
    const int i0 = tid, i1 = tid + 1024, i2 = tid + 2048, i3 = tid + 3072;
    if (i0 < n) { rec0 = win[i0]; atomicAdd(&lhist[((unsigned)rec0[0]) >> 17], 1); }
    if (i1 < n) { rec1 = win[i1]; atomicAdd(&lhist[((unsigned)rec1[0]) >> 17], 1); }
    if (i2 < n) { rec2 = win[i2]; atomicAdd(&lhist[((unsigned)rec2[0]) >> 17], 1); }
    if (i3 < n) { rec3 = win[i3]; atomicAdd(&lhist[((unsigned)rec3[0]) >> 17], 1); }
    __syncthreads();

    // single-wave scan: wave 0, 4 consecutive bins per lane + shuffle scan
    if (tid < 64) {
        int b0 = lhist[tid * 4 + 0], b1 = lhist[tid * 4 + 1];
        int b2 = lhist[tid * 4 + 2], b3 = lhist[tid * 4 + 3];
        int p0 = b0, p1 = p0 + b1, p2 = p1 + b2, p3 = p2 + b3;
        int s = p3;
#pragma unroll
        for (int d = 1; d < 64; d <<= 1) {
            int t2 = __shfl_up(s, d, 64);
            if (tid >= d) s += t2;
        }
        int ex = s - p3;                 // exclusive prefix of this 4-bin group
        send[tid * 4 + 0] = ex + p0;
        send[tid * 4 + 1] = ex + p1;
        send[tid * 4 + 2] = ex + p2;
        send[tid * 4 + 3] = ex + p3;
        lcur[tid * 4 + 0] = ex;
        lcur[tid * 4 + 1] = ex + p0;
        lcur[tid * 4 + 2] = ex + p1;
        lcur[tid * 4 + 3] = ex + p2;
    }
    __syncthreads();

    // scatter registers into row-sorted LDS
    if (i0 < n) { int rl = ((unsigned)rec0[0]) >> 17; lbuf[atomicAdd(&lcur[rl], 1)] = rec0; }
    if (i1 < n) { int rl = ((unsigned)rec1[0]) >> 17; lbuf[atomicAdd(&lcur[rl], 1)] = rec1; }
    if (i2 < n) { int rl = ((unsigned)rec2[0]) >> 17; lbuf[atomicAdd(&lcur[rl], 1)] = rec2; }
    if (i3 < n) { int rl = ((unsigned)rec3[0]) >> 17; lbuf[atomicAdd(&lcur[rl], 1)] = rec3; }
    __syncthreads();

    // per-wave register-accumulator segsum, 8-deep gather pipeline
    const int wave = tid >> 6;
    const int lane = tid & 63;
    const char* hb = (const char*)h;
    const unsigned lo4 = (unsigned)lane * 4u;
    for (int rl = wave; rl < RPB; rl += 16) {
        int gr = b * RPB + rl;
        if (gr >= N_NODES) break;
        int s = rl ? send[rl - 1] : 0;
        int e = send[rl];

        f32x2 acc0 = (f32x2)(0.0f), acc1 = (f32x2)(0.0f);
        f32x2 acc2 = (f32x2)(0.0f), acc3 = (f32x2)(0.0f);
        int i = s;
        for (; i + 7 < e; i += 8) {
            i32x2 r0 = lbuf[i],     r1 = lbuf[i + 1], r2 = lbuf[i + 2], r3 = lbuf[i + 3];
            i32x2 r4 = lbuf[i + 4], r5 = lbuf[i + 5], r6 = lbuf[i + 6], r7 = lbuf[i + 7];
            unsigned o0 = (((unsigned)r0[0] & 0x1FFFFu) << 8) + lo4;
            unsigned o1 = (((unsigned)r1[0] & 0x1FFFFu) << 8) + lo4;
            unsigned o2 = (((unsigned)r2[0] & 0x1FFFFu) << 8) + lo4;
            unsigned o3 = (((unsigned)r3[0] & 0x1FFFFu) << 8) + lo4;
            unsigned o4 = (((unsigned)r4[0] & 0x1FFFFu) << 8) + lo4;
            unsigned o5 = (((unsigned)r5[0] & 0x1FFFFu) << 8) + lo4;
            unsigned o6 = (((unsigned)r6[0] & 0x1FFFFu) << 8) + lo4;
            unsigned o7 = (((unsigned)r7[0] & 0x1FFFFu) << 8) + lo4;
            unsigned u0 = *(const unsigned*)(hb + o0);
            unsigned u1 = *(const unsigned*)(hb + o1);
            unsigned u2 = *(const unsigned*)(hb + o2);
            unsigned u3 = *(const unsigned*)(hb + o3);
            unsigned u4 = *(const unsigned*)(hb + o4);
            unsigned u5 = *(const unsigned*)(hb + o5);
            unsigned u6 = *(const unsigned*)(hb + o6);
            unsigned u7 = *(const unsigned*)(hb + o7);
            acc0 += bf2f(u0) * __int_as_float(r0[1]);
            acc1 += bf2f(u1) * __int_as_float(r1[1]);
            acc2 += bf2f(u2) * __int_as_float(r2[1]);
            acc3 += bf2f(u3) * __int_as_float(r3[1]);
            acc0 += bf2f(u4) * __int_as_float(r4[1]);
            acc1 += bf2f(u5) * __int_as_float(r5[1]);
            acc2 += bf2f(u6) * __int_as_float(r6[1]);
            acc3 += bf2f(u7) * __int_as_float(r7[1]);
        }
        for (; i + 3 < e; i += 4) {
            i32x2 r0 = lbuf[i], r1 = lbuf[i + 1], r2 = lbuf[i + 2], r3 = lbuf[i + 3];
            unsigned o0 = (((unsigned)r0[0] & 0x1FFFFu) << 8) + lo4;
            unsigned o1 = (((unsigned)r1[0] & 0x1FFFFu) << 8) + lo4;
            unsigned o2 = (((unsigned)r2[0] & 0x1FFFFu) << 8) + lo4;
            unsigned o3 = (((unsigned)r3[0] & 0x1FFFFu) << 8) + lo4;
            unsigned u0 = *(const unsigned*)(hb + o0);
            unsigned u1 = *(const unsigned*)(hb + o1);
            unsigned u2 = *(const unsigned*)(hb + o2);
            unsigned u3 = *(const unsigned*)(hb + o3);
            acc0 += bf2f(u0) * __int_as_float(r0[1]);
            acc1 += bf2f(u1) * __int_as_float(r1[1]);
            acc2 += bf2f(u2) * __int_as_float(r2[1]);
            acc3 += bf2f(u3) * __int_as_float(r3[1]);
        }
        for (; i < e; ++i) {
            i32x2 r0 = lbuf[i];
            unsigned o0 = (((unsigned)r0[0] & 0x1FFFFu) << 8) + lo4;
            unsigned u0 = *(const unsigned*)(hb + o0);
            acc0 += bf2f(u0) * __int_as_float(r0[1]);
        }

        f32x2 t01 = acc0 + acc1, t23 = acc2 + acc3;
        f32x2 tt = t01 + t23;
        f32x2 o;
        o[0] = fmaxf(tt[0], 0.0f);
        o[1] = fmaxf(tt[1], 0.0f);
        __builtin_nontemporal_store(o, (f32x2*)(out + (size_t)gr * D + lane * 2));
    }
}

extern "C" void kernel_launch(void* const* d_in, const int* in_sizes, int n_in,
                              void* d_out, int out_size, void* d_ws, size_t ws_size,
                              hipStream_t stream) {
    const float* x    = (const float*)d_in[0];
    const float* w    = (const float*)d_in[1];
    const float* vals = (const float*)d_in[2];
    const int*   rows = (const int*)d_in[3];
    const int*   cols = (const int*)d_in[4];
    float*       out  = (float*)d_out;

    // ---- workspace (~40.3 MB) ----
    char* p = (char*)d_ws;
    __bf16* h         = (__bf16*)p;  p += (size_t)N_NODES * D * 2;          // 25.6 MB
    __bf16* WT        = (__bf16*)p;  p += (size_t)D * D * 2;                // 32 KB
    int*    bucketCnt = (int*)p;     p += 4096;                             // NB ints
    i32x2*  svcA      = (i32x2*)p;   p += (size_t)NB * BCAP * 8;            // 14.7 MB

    prep_kernel<<<64, 256, 0, stream>>>(w, WT, bucketCnt);
    gemm_kernel<<<(N_TILES + 3) / 4, 256, 0, stream>>>(x, WT, h);
    scatterB_kernel<<<SB_BLKS, 1024, 0, stream>>>(rows, cols, vals, bucketCnt, svcA);
    sortsum_kernel<<<NB, 1024, 0, stream>>>(h, bucketCnt, svcA, out);
}

// Round 10
// 212.806 us; speedup vs baseline: 1.5648x; 1.0182x over previous
//
#include <hip/hip_runtime.h>
#include <hip/hip_bf16.h>

#define N_NODES 100000
#define N_EDGES 1600000
#define D 128
#define N_TILES 6250             // N_NODES/16
#define NB 512                   // buckets
#define RPB 196                  // rows per bucket (512*196 = 100352 >= N_NODES)
#define BCAP 3584                // slab capacity: mean 3136 + 8 sigma
#define SB_BLKS 256              // scatterB blocks: 1 per CU, zero tail
#define SB_EDGES 6250            // 256*6250 = 1.6M exact
#define N_PAIRS 3125             // tile pairs (2 tiles per wave)

typedef __bf16 bf16x8 __attribute__((ext_vector_type(8)));
typedef float  f32x4  __attribute__((ext_vector_type(4)));
typedef float  f32x2  __attribute__((ext_vector_type(2)));
typedef int    i32x2  __attribute__((ext_vector_type(2)));

// ---- K1: W transpose (fp32 -> bf16 WT) + zero bucket cursors ----
__global__ __launch_bounds__(256) void prep_kernel(const float* __restrict__ W,
                                                   __bf16* __restrict__ WT,
                                                   int* __restrict__ bucketCnt) {
    int t = blockIdx.x * 256 + threadIdx.x;   // 16384 threads
    int k = t >> 7, n = t & 127;
    WT[n * D + k] = (__bf16)W[t];
    if (t < NB) bucketCnt[t] = 0;
}

// ---- K2: GEMM h = bf16(x) @ bf16(W), 2 tiles per wave ----
// Each wave computes two 16-row tiles sharing the SAME WT fragments:
// halves WT L2 re-reads (200 MB -> 100 MB) and doubles x-load MLP
// (4 outstanding 16B loads per kk). acc fully static-indexed; VGPR ~110
// under the (256,4) 128-VGPR cap. NT x-loads (zero reuse, keep L2 for h).
__global__ __launch_bounds__(256, 4) void gemm_kernel(
        const float* __restrict__ x,
        const __bf16* __restrict__ WT,
        __bf16* __restrict__ h) {
    __shared__ __bf16 lsm[4][16][144];
    const int wave = threadIdx.x >> 6;
    const int lane = threadIdx.x & 63;
    const int pair = blockIdx.x * 4 + wave;
    if (pair >= N_PAIRS) return;
    const int t0 = pair * 2, t1 = pair * 2 + 1;   // both < N_TILES (6250 even)
    const int m = lane & 15, quad = lane >> 4;
    const float* xp0 = x + (size_t)(t0 * 16 + m) * D + quad * 8;
    const float* xp1 = x + (size_t)(t1 * 16 + m) * D + quad * 8;

    f32x4 acc0[8], acc1[8];
#pragma unroll
    for (int ct = 0; ct < 8; ++ct) { acc0[ct] = (f32x4)(0.0f); acc1[ct] = (f32x4)(0.0f); }
#pragma unroll
    for (int kk = 0; kk < 4; ++kk) {
        f32x4 a00 = __builtin_nontemporal_load((const f32x4*)(xp0 + kk * 32));
        f32x4 a01 = __builtin_nontemporal_load((const f32x4*)(xp0 + kk * 32 + 4));
        f32x4 a10 = __builtin_nontemporal_load((const f32x4*)(xp1 + kk * 32));
        f32x4 a11 = __builtin_nontemporal_load((const f32x4*)(xp1 + kk * 32 + 4));
        bf16x8 a0, a1;
#pragma unroll
        for (int j = 0; j < 4; ++j) {
            a0[j] = (__bf16)a00[j]; a0[j + 4] = (__bf16)a01[j];
            a1[j] = (__bf16)a10[j]; a1[j + 4] = (__bf16)a11[j];
        }
#pragma unroll
        for (int ct = 0; ct < 8; ++ct) {
            bf16x8 b = *(const bf16x8*)(WT + (size_t)(ct * 16 + m) * D + kk * 32 + quad * 8);
            acc0[ct] = __builtin_amdgcn_mfma_f32_16x16x32_bf16(a0, b, acc0[ct], 0, 0, 0);
            acc1[ct] = __builtin_amdgcn_mfma_f32_16x16x32_bf16(a1, b, acc1[ct], 0, 0, 0);
        }
    }
    // epilogue tile0 then tile1 through the wave-private lsm slice
#pragma unroll
    for (int ct = 0; ct < 8; ++ct)
#pragma unroll
        for (int r = 0; r < 4; ++r)
            lsm[wave][quad * 4 + r][ct * 16 + m] = (__bf16)acc0[ct][r];
#pragma unroll
    for (int i = 0; i < 4; ++i) {
        int rl = i * 4 + quad;
        bf16x8 vv = *(const bf16x8*)&lsm[wave][rl][m * 8];
        *(bf16x8*)(h + (size_t)(t0 * 16 + rl) * D + m * 8) = vv;
    }
#pragma unroll
    for (int ct = 0; ct < 8; ++ct)
#pragma unroll
        for (int r = 0; r < 4; ++r)
            lsm[wave][quad * 4 + r][ct * 16 + m] = (__bf16)acc1[ct][r];
#pragma unroll
    for (int i = 0; i < 4; ++i) {
        int rl = i * 4 + quad;
        bf16x8 vv = *(const bf16x8*)&lsm[wave][rl][m * 8];
        *(bf16x8*)(h + (size_t)(t1 * 16 + rl) * D + m * 8) = vv;
    }
}

// ---- K3: scatterB — exact LDS counting sort + cooperative drain (R9-proven) ----
__global__ __launch_bounds__(1024, 8) void scatterB_kernel(
        const int* __restrict__ rows, const int* __restrict__ cols,
        const float* __restrict__ vals,
        int* __restrict__ bucketCnt, i32x2* __restrict__ svcA) {
    __shared__ i32x2 lbuf[SB_EDGES];   // 50000 B
    __shared__ int   lhist[NB];        // counts (preserved)
    __shared__ int   sstart[NB];       // exclusive starts
    __shared__ int   lcur[NB];         // scatter cursors, then g broadcast
    const int tid  = threadIdx.x;
    const int base = blockIdx.x * SB_EDGES;

    if (tid < NB) lhist[tid] = 0;
    __syncthreads();

    i32x2 r0, r1, r2, r3, r4, r5, r6;
    int   b0, b1, b2, b3, b4, b5, b6;
#define LOADREC(K, RK, BK)                                             \
    {                                                                  \
        int e = base + tid + (K) * 1024;                               \
        int rr = rows[e];                                              \
        BK = rr / RPB;                                                 \
        int local = rr - BK * RPB;                                     \
        RK[0] = (local << 17) | cols[e];                               \
        RK[1] = __float_as_int(vals[e]);                               \
        atomicAdd(&lhist[BK], 1);                                      \
    }
    LOADREC(0, r0, b0) LOADREC(1, r1, b1) LOADREC(2, r2, b2)
    LOADREC(3, r3, b3) LOADREC(4, r4, b4) LOADREC(5, r5, b5)
    if (tid < SB_EDGES - 6 * 1024) { LOADREC(6, r6, b6) }
#undef LOADREC
    __syncthreads();

    if (tid < 64) {
        const int bb = tid * 8;
        int run = 0;
#pragma unroll
        for (int j = 0; j < 8; ++j) run += lhist[bb + j];
        int s = run;
#pragma unroll
        for (int d = 1; d < 64; d <<= 1) {
            int t2 = __shfl_up(s, d, 64);
            if (tid >= d) s += t2;
        }
        int ex = s - run;
#pragma unroll
        for (int j = 0; j < 8; ++j) {
            sstart[bb + j] = ex;
            lcur[bb + j]   = ex;
            ex += lhist[bb + j];
        }
    }
    __syncthreads();

    lbuf[atomicAdd(&lcur[b0], 1)] = r0;
    lbuf[atomicAdd(&lcur[b1], 1)] = r1;
    lbuf[atomicAdd(&lcur[b2], 1)] = r2;
    lbuf[atomicAdd(&lcur[b3], 1)] = r3;
    lbuf[atomicAdd(&lcur[b4], 1)] = r4;
    lbuf[atomicAdd(&lcur[b5], 1)] = r5;
    if (tid < SB_EDGES - 6 * 1024) lbuf[atomicAdd(&lcur[b6], 1)] = r6;
    __syncthreads();

    if (tid < NB) {
        int n = lhist[tid];
        if (n > 0) lcur[tid] = atomicAdd(&bucketCnt[tid], n);   // reuse lcur as g
    }
    __syncthreads();

    {
        const int bkt  = tid >> 1;
        const int half = tid & 1;
        int n = lhist[bkt];
        if (n > 0) {
            int g = lcur[bkt];
            int s = sstart[bkt];
            i32x2* dst = svcA + (size_t)bkt * BCAP;
            for (int i = half; i < n; i += 2)
                if (g + i < BCAP) dst[g + i] = lbuf[s + i];
        }
    }
}

// ---- K4: fused local sort + segsum + relu (R1-proven, 64us, untouched) ----
__device__ __forceinline__ f32x2 bf2f(unsigned u) {
    f32x2 r;
    r[0] = __int_as_float(u << 16);
    r[1] = __int_as_float(u & 0xffff0000u);
    return r;
}

__global__ __launch_bounds__(1024, 8) void sortsum_kernel(
        const __bf16* __restrict__ h, const int* __restrict__ bucketCnt,
        const i32x2* __restrict__ svcA, float* __restrict__ out) {
    __shared__ i32x2 lbuf[BCAP];     // 28 KB
    __shared__ int   lhist[256];
    __shared__ int   send[256];      // inclusive scan (row ends)
    __shared__ int   lcur[256];      // scatter cursors (row starts, mutated)
    const int b   = blockIdx.x;
    const int tid = threadIdx.x;
    const int n   = min(bucketCnt[b], BCAP);
    const i32x2* win = svcA + (size_t)b * BCAP;

    if (tid < 256) lhist[tid] = 0;
    __syncthreads();

    i32x2 rec0, rec1, rec2, rec3;
    const int i0 = tid, i1 = tid + 1024, i2 = tid + 2048, i3 = tid + 3072;
    if (i0 < n) { rec0 = win[i0]; atomicAdd(&lhist[((unsigned)rec0[0]) >> 17], 1); }
    if (i1 < n) { rec1 = win[i1]; atomicAdd(&lhist[((unsigned)rec1[0]) >> 17], 1); }
    if (i2 < n) { rec2 = win[i2]; atomicAdd(&lhist[((unsigned)rec2[0]) >> 17], 1); }
    if (i3 < n) { rec3 = win[i3]; atomicAdd(&lhist[((unsigned)rec3[0]) >> 17], 1); }
    __syncthreads();

    if (tid < 64) {
        int b0 = lhist[tid * 4 + 0], b1 = lhist[tid * 4 + 1];
        int b2 = lhist[tid * 4 + 2], b3 = lhist[tid * 4 + 3];
        int p0 = b0, p1 = p0 + b1, p2 = p1 + b2, p3 = p2 + b3;
        int s = p3;
#pragma unroll
        for (int d = 1; d < 64; d <<= 1) {
            int t2 = __shfl_up(s, d, 64);
            if (tid >= d) s += t2;
        }
        int ex = s - p3;
        send[tid * 4 + 0] = ex + p0;
        send[tid * 4 + 1] = ex + p1;
        send[tid * 4 + 2] = ex + p2;
        send[tid * 4 + 3] = ex + p3;
        lcur[tid * 4 + 0] = ex;
        lcur[tid * 4 + 1] = ex + p0;
        lcur[tid * 4 + 2] = ex + p1;
        lcur[tid * 4 + 3] = ex + p2;
    }
    __syncthreads();

    if (i0 < n) { int rl = ((unsigned)rec0[0]) >> 17; lbuf[atomicAdd(&lcur[rl], 1)] = rec0; }
    if (i1 < n) { int rl = ((unsigned)rec1[0]) >> 17; lbuf[atomicAdd(&lcur[rl], 1)] = rec1; }
    if (i2 < n) { int rl = ((unsigned)rec2[0]) >> 17; lbuf[atomicAdd(&lcur[rl], 1)] = rec2; }
    if (i3 < n) { int rl = ((unsigned)rec3[0]) >> 17; lbuf[atomicAdd(&lcur[rl], 1)] = rec3; }
    __syncthreads();

    const int wave = tid >> 6;
    const int lane = tid & 63;
    const char* hb = (const char*)h;
    const unsigned lo4 = (unsigned)lane * 4u;
    for (int rl = wave; rl < RPB; rl += 16) {
        int gr = b * RPB + rl;
        if (gr >= N_NODES) break;
        int s = rl ? send[rl - 1] : 0;
        int e = send[rl];

        f32x2 acc0 = (f32x2)(0.0f), acc1 = (f32x2)(0.0f);
        f32x2 acc2 = (f32x2)(0.0f), acc3 = (f32x2)(0.0f);
        int i = s;
        for (; i + 7 < e; i += 8) {
            i32x2 r0 = lbuf[i],     r1 = lbuf[i + 1], r2 = lbuf[i + 2], r3 = lbuf[i + 3];
            i32x2 r4 = lbuf[i + 4], r5 = lbuf[i + 5], r6 = lbuf[i + 6], r7 = lbuf[i + 7];
            unsigned o0 = (((unsigned)r0[0] & 0x1FFFFu) << 8) + lo4;
            unsigned o1 = (((unsigned)r1[0] & 0x1FFFFu) << 8) + lo4;
            unsigned o2 = (((unsigned)r2[0] & 0x1FFFFu) << 8) + lo4;
            unsigned o3 = (((unsigned)r3[0] & 0x1FFFFu) << 8) + lo4;
            unsigned o4 = (((unsigned)r4[0] & 0x1FFFFu) << 8) + lo4;
            unsigned o5 = (((unsigned)r5[0] & 0x1FFFFu) << 8) + lo4;
            unsigned o6 = (((unsigned)r6[0] & 0x1FFFFu) << 8) + lo4;
            unsigned o7 = (((unsigned)r7[0] & 0x1FFFFu) << 8) + lo4;
            unsigned u0 = *(const unsigned*)(hb + o0);
            unsigned u1 = *(const unsigned*)(hb + o1);
            unsigned u2 = *(const unsigned*)(hb + o2);
            unsigned u3 = *(const unsigned*)(hb + o3);
            unsigned u4 = *(const unsigned*)(hb + o4);
            unsigned u5 = *(const unsigned*)(hb + o5);
            unsigned u6 = *(const unsigned*)(hb + o6);
            unsigned u7 = *(const unsigned*)(hb + o7);
            acc0 += bf2f(u0) * __int_as_float(r0[1]);
            acc1 += bf2f(u1) * __int_as_float(r1[1]);
            acc2 += bf2f(u2) * __int_as_float(r2[1]);
            acc3 += bf2f(u3) * __int_as_float(r3[1]);
            acc0 += bf2f(u4) * __int_as_float(r4[1]);
            acc1 += bf2f(u5) * __int_as_float(r5[1]);
            acc2 += bf2f(u6) * __int_as_float(r6[1]);
            acc3 += bf2f(u7) * __int_as_float(r7[1]);
        }
        for (; i + 3 < e; i += 4) {
            i32x2 r0 = lbuf[i], r1 = lbuf[i + 1], r2 = lbuf[i + 2], r3 = lbuf[i + 3];
            unsigned o0 = (((unsigned)r0[0] & 0x1FFFFu) << 8) + lo4;
            unsigned o1 = (((unsigned)r1[0] & 0x1FFFFu) << 8) + lo4;
            unsigned o2 = (((unsigned)r2[0] & 0x1FFFFu) << 8) + lo4;
            unsigned o3 = (((unsigned)r3[0] & 0x1FFFFu) << 8) + lo4;
            unsigned u0 = *(const unsigned*)(hb + o0);
            unsigned u1 = *(const unsigned*)(hb + o1);
            unsigned u2 = *(const unsigned*)(hb + o2);
            unsigned u3 = *(const unsigned*)(hb + o3);
            acc0 += bf2f(u0) * __int_as_float(r0[1]);
            acc1 += bf2f(u1) * __int_as_float(r1[1]);
            acc2 += bf2f(u2) * __int_as_float(r2[1]);
            acc3 += bf2f(u3) * __int_as_float(r3[1]);
        }
        for (; i < e; ++i) {
            i32x2 r0 = lbuf[i];
            unsigned o0 = (((unsigned)r0[0] & 0x1FFFFu) << 8) + lo4;
            unsigned u0 = *(const unsigned*)(hb + o0);
            acc0 += bf2f(u0) * __int_as_float(r0[1]);
        }

        f32x2 t01 = acc0 + acc1, t23 = acc2 + acc3;
        f32x2 tt = t01 + t23;
        f32x2 o;
        o[0] = fmaxf(tt[0], 0.0f);
        o[1] = fmaxf(tt[1], 0.0f);
        __builtin_nontemporal_store(o, (f32x2*)(out + (size_t)gr * D + lane * 2));
    }
}

extern "C" void kernel_launch(void* const* d_in, const int* in_sizes, int n_in,
                              void* d_out, int out_size, void* d_ws, size_t ws_size,
                              hipStream_t stream) {
    const float* x    = (const float*)d_in[0];
    const float* w    = (const float*)d_in[1];
    const float* vals = (const float*)d_in[2];
    const int*   rows = (const int*)d_in[3];
    const int*   cols = (const int*)d_in[4];
    float*       out  = (float*)d_out;

    // ---- workspace (~40.3 MB) ----
    char* p = (char*)d_ws;
    __bf16* h         = (__bf16*)p;  p += (size_t)N_NODES * D * 2;          // 25.6 MB
    __bf16* WT        = (__bf16*)p;  p += (size_t)D * D * 2;                // 32 KB
    int*    bucketCnt = (int*)p;     p += 4096;                             // NB ints
    i32x2*  svcA      = (i32x2*)p;   p += (size_t)NB * BCAP * 8;            // 14.7 MB

    prep_kernel<<<64, 256, 0, stream>>>(w, WT, bucketCnt);
    gemm_kernel<<<(N_PAIRS + 3) / 4, 256, 0, stream>>>(x, WT, h);
    scatterB_kernel<<<SB_BLKS, 1024, 0, stream>>>(rows, cols, vals, bucketCnt, svcA);
    sortsum_kernel<<<NB, 1024, 0, stream>>>(h, bucketCnt, svcA, out);
}

// Round 11
// 209.590 us; speedup vs baseline: 1.5888x; 1.0153x over previous
//
#include <hip/hip_runtime.h>
#include <hip/hip_bf16.h>

#define N_NODES 100000
#define N_EDGES 1600000
#define D 128
#define N_TILES 6250             // N_NODES/16
#define NB 512                   // buckets
#define RPB 196                  // rows per bucket (512*196 = 100352 >= N_NODES)
#define BCAP 3584                // slab capacity: mean 3136 + 8 sigma
#define SB_BLKS 256              // scatterB blocks: 1 per CU, zero tail
#define SB_EDGES 6250            // 256*6250 = 1.6M exact
#define N_TRIPLES 2084           // tile triples (3 tiles per wave; 2084*3 = 6252 >= 6250)

typedef __bf16 bf16x8 __attribute__((ext_vector_type(8)));
typedef float  f32x4  __attribute__((ext_vector_type(4)));
typedef float  f32x2  __attribute__((ext_vector_type(2)));
typedef int    i32x2  __attribute__((ext_vector_type(2)));

// ---- K1: W transpose (fp32 -> bf16 WT) + zero bucket cursors ----
__global__ __launch_bounds__(256) void prep_kernel(const float* __restrict__ W,
                                                   __bf16* __restrict__ WT,
                                                   int* __restrict__ bucketCnt) {
    int t = blockIdx.x * 256 + threadIdx.x;   // 16384 threads
    int k = t >> 7, n = t & 127;
    WT[n * D + k] = (__bf16)W[t];
    if (t < NB) bucketCnt[t] = 0;
}

// ---- K2: GEMM h = bf16(x) @ bf16(W), 3 tiles per wave ----
// Third notch of the proven R9/R10 mechanism: each WT fragment feeds 3
// MFMAs (WT L2 traffic 100 -> 67 MB) and 6 NT x-loads are in flight per
// kk. acc = 96 VGPR, all static-indexed; (256,3) gives a 170-VGPR cap
// (R2-R4 lesson: the spill tell is VGPR_Count collapsing to ~32).
__global__ __launch_bounds__(256, 3) void gemm_kernel(
        const float* __restrict__ x,
        const __bf16* __restrict__ WT,
        __bf16* __restrict__ h) {
    __shared__ __bf16 lsm[4][16][144];
    const int wave = threadIdx.x >> 6;
    const int lane = threadIdx.x & 63;
    const int triple = blockIdx.x * 4 + wave;
    if (triple >= N_TRIPLES) return;
    const int t0 = triple * 3, t1 = t0 + 1, t2 = t0 + 2;
    const bool v1 = (t1 < N_TILES), v2 = (t2 < N_TILES);
    const int m = lane & 15, quad = lane >> 4;
    const float* xp0 = x + (size_t)(t0 * 16 + m) * D + quad * 8;
    const float* xp1 = x + (size_t)((v1 ? t1 * 16 : 0) + m) * D + quad * 8;  // clamped if invalid
    const float* xp2 = x + (size_t)((v2 ? t2 * 16 : 0) + m) * D + quad * 8;

    f32x4 acc0[8], acc1[8], acc2[8];
#pragma unroll
    for (int ct = 0; ct < 8; ++ct) {
        acc0[ct] = (f32x4)(0.0f); acc1[ct] = (f32x4)(0.0f); acc2[ct] = (f32x4)(0.0f);
    }
#pragma unroll
    for (int kk = 0; kk < 4; ++kk) {
        f32x4 a00 = __builtin_nontemporal_load((const f32x4*)(xp0 + kk * 32));
        f32x4 a01 = __builtin_nontemporal_load((const f32x4*)(xp0 + kk * 32 + 4));
        f32x4 a10 = __builtin_nontemporal_load((const f32x4*)(xp1 + kk * 32));
        f32x4 a11 = __builtin_nontemporal_load((const f32x4*)(xp1 + kk * 32 + 4));
        f32x4 a20 = __builtin_nontemporal_load((const f32x4*)(xp2 + kk * 32));
        f32x4 a21 = __builtin_nontemporal_load((const f32x4*)(xp2 + kk * 32 + 4));
        bf16x8 a0, a1, a2;
#pragma unroll
        for (int j = 0; j < 4; ++j) {
            a0[j] = (__bf16)a00[j]; a0[j + 4] = (__bf16)a01[j];
            a1[j] = (__bf16)a10[j]; a1[j + 4] = (__bf16)a11[j];
            a2[j] = (__bf16)a20[j]; a2[j + 4] = (__bf16)a21[j];
        }
#pragma unroll
        for (int ct = 0; ct < 8; ++ct) {
            bf16x8 b = *(const bf16x8*)(WT + (size_t)(ct * 16 + m) * D + kk * 32 + quad * 8);
            acc0[ct] = __builtin_amdgcn_mfma_f32_16x16x32_bf16(a0, b, acc0[ct], 0, 0, 0);
            acc1[ct] = __builtin_amdgcn_mfma_f32_16x16x32_bf16(a1, b, acc1[ct], 0, 0, 0);
            acc2[ct] = __builtin_amdgcn_mfma_f32_16x16x32_bf16(a2, b, acc2[ct], 0, 0, 0);
        }
    }
    // epilogue through the wave-private lsm slice (no barrier needed: LDS
    // ops within one wave are in-order via compiler lgkmcnt waits)
#define EPI(ACC, T)                                                          \
    {                                                                        \
        _Pragma("unroll")                                                    \
        for (int ct = 0; ct < 8; ++ct)                                       \
            _Pragma("unroll")                                                \
            for (int r = 0; r < 4; ++r)                                      \
                lsm[wave][quad * 4 + r][ct * 16 + m] = (__bf16)ACC[ct][r];   \
        _Pragma("unroll")                                                    \
        for (int i = 0; i < 4; ++i) {                                        \
            int rl = i * 4 + quad;                                           \
            bf16x8 vv = *(const bf16x8*)&lsm[wave][rl][m * 8];               \
            *(bf16x8*)(h + (size_t)((T) * 16 + rl) * D + m * 8) = vv;        \
        }                                                                    \
    }
    EPI(acc0, t0)
    if (v1) EPI(acc1, t1)
    if (v2) EPI(acc2, t2)
#undef EPI
}

// ---- K3: scatterB — exact LDS counting sort + cooperative drain (R9-proven) ----
__global__ __launch_bounds__(1024, 8) void scatterB_kernel(
        const int* __restrict__ rows, const int* __restrict__ cols,
        const float* __restrict__ vals,
        int* __restrict__ bucketCnt, i32x2* __restrict__ svcA) {
    __shared__ i32x2 lbuf[SB_EDGES];   // 50000 B
    __shared__ int   lhist[NB];        // counts (preserved)
    __shared__ int   sstart[NB];       // exclusive starts
    __shared__ int   lcur[NB];         // scatter cursors, then g broadcast
    const int tid  = threadIdx.x;
    const int base = blockIdx.x * SB_EDGES;

    if (tid < NB) lhist[tid] = 0;
    __syncthreads();

    i32x2 r0, r1, r2, r3, r4, r5, r6;
    int   b0, b1, b2, b3, b4, b5, b6;
#define LOADREC(K, RK, BK)                                             \
    {                                                                  \
        int e = base + tid + (K) * 1024;                               \
        int rr = rows[e];                                              \
        BK = rr / RPB;                                                 \
        int local = rr - BK * RPB;                                     \
        RK[0] = (local << 17) | cols[e];                               \
        RK[1] = __float_as_int(vals[e]);                               \
        atomicAdd(&lhist[BK], 1);                                      \
    }
    LOADREC(0, r0, b0) LOADREC(1, r1, b1) LOADREC(2, r2, b2)
    LOADREC(3, r3, b3) LOADREC(4, r4, b4) LOADREC(5, r5, b5)
    if (tid < SB_EDGES - 6 * 1024) { LOADREC(6, r6, b6) }
#undef LOADREC
    __syncthreads();

    if (tid < 64) {
        const int bb = tid * 8;
        int run = 0;
#pragma unroll
        for (int j = 0; j < 8; ++j) run += lhist[bb + j];
        int s = run;
#pragma unroll
        for (int d = 1; d < 64; d <<= 1) {
            int t2 = __shfl_up(s, d, 64);
            if (tid >= d) s += t2;
        }
        int ex = s - run;
#pragma unroll
        for (int j = 0; j < 8; ++j) {
            sstart[bb + j] = ex;
            lcur[bb + j]   = ex;
            ex += lhist[bb + j];
        }
    }
    __syncthreads();

    lbuf[atomicAdd(&lcur[b0], 1)] = r0;
    lbuf[atomicAdd(&lcur[b1], 1)] = r1;
    lbuf[atomicAdd(&lcur[b2], 1)] = r2;
    lbuf[atomicAdd(&lcur[b3], 1)] = r3;
    lbuf[atomicAdd(&lcur[b4], 1)] = r4;
    lbuf[atomicAdd(&lcur[b5], 1)] = r5;
    if (tid < SB_EDGES - 6 * 1024) lbuf[atomicAdd(&lcur[b6], 1)] = r6;
    __syncthreads();

    if (tid < NB) {
        int n = lhist[tid];
        if (n > 0) lcur[tid] = atomicAdd(&bucketCnt[tid], n);   // reuse lcur as g
    }
    __syncthreads();

    {
        const int bkt  = tid >> 1;
        const int half = tid & 1;
        int n = lhist[bkt];
        if (n > 0) {
            int g = lcur[bkt];
            int s = sstart[bkt];
            i32x2* dst = svcA + (size_t)bkt * BCAP;
            for (int i = half; i < n; i += 2)
                if (g + i < BCAP) dst[g + i] = lbuf[s + i];
        }
    }
}

// ---- K4: fused local sort + segsum + relu (R1-proven, ~65us, untouched) ----
__device__ __forceinline__ f32x2 bf2f(unsigned u) {
    f32x2 r;
    r[0] = __int_as_float(u << 16);
    r[1] = __int_as_float(u & 0xffff0000u);
    return r;
}

__global__ __launch_bounds__(1024, 8) void sortsum_kernel(
        const __bf16* __restrict__ h, const int* __restrict__ bucketCnt,
        const i32x2* __restrict__ svcA, float* __restrict__ out) {
    __shared__ i32x2 lbuf[BCAP];     // 28 KB
    __shared__ int   lhist[256];
    __shared__ int   send[256];      // inclusive scan (row ends)
    __shared__ int   lcur[256];      // scatter cursors (row starts, mutated)
    const int b   = blockIdx.x;
    const int tid = threadIdx.x;
    const int n   = min(bucketCnt[b], BCAP);
    const i32x2* win = svcA + (size_t)b * BCAP;

    if (tid < 256) lhist[tid] = 0;
    __syncthreads();

    i32x2 rec0, rec1, rec2, rec3;
    const int i0 = tid, i1 = tid + 1024, i2 = tid + 2048, i3 = tid + 3072;
    if (i0 < n) { rec0 = win[i0]; atomicAdd(&lhist[((unsigned)rec0[0]) >> 17], 1); }
    if (i1 < n) { rec1 = win[i1]; atomicAdd(&lhist[((unsigned)rec1[0]) >> 17], 1); }
    if (i2 < n) { rec2 = win[i2]; atomicAdd(&lhist[((unsigned)rec2[0]) >> 17], 1); }
    if (i3 < n) { rec3 = win[i3]; atomicAdd(&lhist[((unsigned)rec3[0]) >> 17], 1); }
    __syncthreads();

    if (tid < 64) {
        int b0 = lhist[tid * 4 + 0], b1 = lhist[tid * 4 + 1];
        int b2 = lhist[tid * 4 + 2], b3 = lhist[tid * 4 + 3];
        int p0 = b0, p1 = p0 + b1, p2 = p1 + b2, p3 = p2 + b3;
        int s = p3;
#pragma unroll
        for (int d = 1; d < 64; d <<= 1) {
            int t2 = __shfl_up(s, d, 64);
            if (tid >= d) s += t2;
        }
        int ex = s - p3;
        send[tid * 4 + 0] = ex + p0;
        send[tid * 4 + 1] = ex + p1;
        send[tid * 4 + 2] = ex + p2;
        send[tid * 4 + 3] = ex + p3;
        lcur[tid * 4 + 0] = ex;
        lcur[tid * 4 + 1] = ex + p0;
        lcur[tid * 4 + 2] = ex + p1;
        lcur[tid * 4 + 3] = ex + p2;
    }
    __syncthreads();

    if (i0 < n) { int rl = ((unsigned)rec0[0]) >> 17; lbuf[atomicAdd(&lcur[rl], 1)] = rec0; }
    if (i1 < n) { int rl = ((unsigned)rec1[0]) >> 17; lbuf[atomicAdd(&lcur[rl], 1)] = rec1; }
    if (i2 < n) { int rl = ((unsigned)rec2[0]) >> 17; lbuf[atomicAdd(&lcur[rl], 1)] = rec2; }
    if (i3 < n) { int rl = ((unsigned)rec3[0]) >> 17; lbuf[atomicAdd(&lcur[rl], 1)] = rec3; }
    __syncthreads();

    const int wave = tid >> 6;
    const int lane = tid & 63;
    const char* hb = (const char*)h;
    const unsigned lo4 = (unsigned)lane * 4u;
    for (int rl = wave; rl < RPB; rl += 16) {
        int gr = b * RPB + rl;
        if (gr >= N_NODES) break;
        int s = rl ? send[rl - 1] : 0;
        int e = send[rl];

        f32x2 acc0 = (f32x2)(0.0f), acc1 = (f32x2)(0.0f);
        f32x2 acc2 = (f32x2)(0.0f), acc3 = (f32x2)(0.0f);
        int i = s;
        for (; i + 7 < e; i += 8) {
            i32x2 r0 = lbuf[i],     r1 = lbuf[i + 1], r2 = lbuf[i + 2], r3 = lbuf[i + 3];
            i32x2 r4 = lbuf[i + 4], r5 = lbuf[i + 5], r6 = lbuf[i + 6], r7 = lbuf[i + 7];
            unsigned o0 = (((unsigned)r0[0] & 0x1FFFFu) << 8) + lo4;
            unsigned o1 = (((unsigned)r1[0] & 0x1FFFFu) << 8) + lo4;
            unsigned o2 = (((unsigned)r2[0] & 0x1FFFFu) << 8) + lo4;
            unsigned o3 = (((unsigned)r3[0] & 0x1FFFFu) << 8) + lo4;
            unsigned o4 = (((unsigned)r4[0] & 0x1FFFFu) << 8) + lo4;
            unsigned o5 = (((unsigned)r5[0] & 0x1FFFFu) << 8) + lo4;
            unsigned o6 = (((unsigned)r6[0] & 0x1FFFFu) << 8) + lo4;
            unsigned o7 = (((unsigned)r7[0] & 0x1FFFFu) << 8) + lo4;
            unsigned u0 = *(const unsigned*)(hb + o0);
            unsigned u1 = *(const unsigned*)(hb + o1);
            unsigned u2 = *(const unsigned*)(hb + o2);
            unsigned u3 = *(const unsigned*)(hb + o3);
            unsigned u4 = *(const unsigned*)(hb + o4);
            unsigned u5 = *(const unsigned*)(hb + o5);
            unsigned u6 = *(const unsigned*)(hb + o6);
            unsigned u7 = *(const unsigned*)(hb + o7);
            acc0 += bf2f(u0) * __int_as_float(r0[1]);
            acc1 += bf2f(u1) * __int_as_float(r1[1]);
            acc2 += bf2f(u2) * __int_as_float(r2[1]);
            acc3 += bf2f(u3) * __int_as_float(r3[1]);
            acc0 += bf2f(u4) * __int_as_float(r4[1]);
            acc1 += bf2f(u5) * __int_as_float(r5[1]);
            acc2 += bf2f(u6) * __int_as_float(r6[1]);
            acc3 += bf2f(u7) * __int_as_float(r7[1]);
        }
        for (; i + 3 < e; i += 4) {
            i32x2 r0 = lbuf[i], r1 = lbuf[i + 1], r2 = lbuf[i + 2], r3 = lbuf[i + 3];
            unsigned o0 = (((unsigned)r0[0] & 0x1FFFFu) << 8) + lo4;
            unsigned o1 = (((unsigned)r1[0] & 0x1FFFFu) << 8) + lo4;
            unsigned o2 = (((unsigned)r2[0] & 0x1FFFFu) << 8) + lo4;
            unsigned o3 = (((unsigned)r3[0] & 0x1FFFFu) << 8) + lo4;
            unsigned u0 = *(const unsigned*)(hb + o0);
            unsigned u1 = *(const unsigned*)(hb + o1);
            unsigned u2 = *(const unsigned*)(hb + o2);
            unsigned u3 = *(const unsigned*)(hb + o3);
            acc0 += bf2f(u0) * __int_as_float(r0[1]);
            acc1 += bf2f(u1) * __int_as_float(r1[1]);
            acc2 += bf2f(u2) * __int_as_float(r2[1]);
            acc3 += bf2f(u3) * __int_as_float(r3[1]);
        }
        for (; i < e; ++i) {
            i32x2 r0 = lbuf[i];
            unsigned o0 = (((unsigned)r0[0] & 0x1FFFFu) << 8) + lo4;
            unsigned u0 = *(const unsigned*)(hb + o0);
            acc0 += bf2f(u0) * __int_as_float(r0[1]);
        }

        f32x2 t01 = acc0 + acc1, t23 = acc2 + acc3;
        f32x2 tt = t01 + t23;
        f32x2 o;
        o[0] = fmaxf(tt[0], 0.0f);
        o[1] = fmaxf(tt[1], 0.0f);
        __builtin_nontemporal_store(o, (f32x2*)(out + (size_t)gr * D + lane * 2));
    }
}

extern "C" void kernel_launch(void* const* d_in, const int* in_sizes, int n_in,
                              void* d_out, int out_size, void* d_ws, size_t ws_size,
                              hipStream_t stream) {
    const float* x    = (const float*)d_in[0];
    const float* w    = (const float*)d_in[1];
    const float* vals = (const float*)d_in[2];
    const int*   rows = (const int*)d_in[3];
    const int*   cols = (const int*)d_in[4];
    float*       out  = (float*)d_out;

    // ---- workspace (~40.3 MB) ----
    char* p = (char*)d_ws;
    __bf16* h         = (__bf16*)p;  p += (size_t)N_NODES * D * 2;          // 25.6 MB
    __bf16* WT        = (__bf16*)p;  p += (size_t)D * D * 2;                // 32 KB
    int*    bucketCnt = (int*)p;     p += 4096;                             // NB ints
    i32x2*  svcA      = (i32x2*)p;   p += (size_t)NB * BCAP * 8;            // 14.7 MB

    prep_kernel<<<64, 256, 0, stream>>>(w, WT, bucketCnt);
    gemm_kernel<<<(N_TRIPLES + 3) / 4, 256, 0, stream>>>(x, WT, h);
    scatterB_kernel<<<SB_BLKS, 1024, 0, stream>>>(rows, cols, vals, bucketCnt, svcA);
    sortsum_kernel<<<NB, 1024, 0, stream>>>(h, bucketCnt, svcA, out);
}

// Round 12
// 206.268 us; speedup vs baseline: 1.6144x; 1.0161x over previous
//
#include <hip/hip_runtime.h>
#include <hip/hip_bf16.h>

#define N_NODES 100000
#define N_EDGES 1600000
#define D 128
#define N_TILES 6250             // N_NODES/16
#define NB 512                   // buckets
#define RPB 196                  // rows per bucket (512*196 = 100352 >= N_NODES)
#define BCAP 3584                // slab capacity: mean 3136 + 8 sigma
#define SB_BLKS 256              // scatterB blocks: 1 per CU, zero tail
#define SB_EDGES 6250            // 256*6250 = 1.6M exact
#define N_QUADT 1563             // tile quads (4 tiles per wave; 1563*4 = 6252 >= 6250)

typedef __bf16 bf16x8 __attribute__((ext_vector_type(8)));
typedef float  f32x4  __attribute__((ext_vector_type(4)));
typedef float  f32x2  __attribute__((ext_vector_type(2)));
typedef int    i32x2  __attribute__((ext_vector_type(2)));

// ---- K1: W transpose (fp32 -> bf16 WT) + zero bucket cursors ----
__global__ __launch_bounds__(256) void prep_kernel(const float* __restrict__ W,
                                                   __bf16* __restrict__ WT,
                                                   int* __restrict__ bucketCnt) {
    int t = blockIdx.x * 256 + threadIdx.x;   // 16384 threads
    int k = t >> 7, n = t & 127;
    WT[n * D + k] = (__bf16)W[t];
    if (t < NB) bucketCnt[t] = 0;
}

// ---- K2: GEMM h = bf16(x) @ bf16(W), 4 tiles per wave ----
// Fourth notch of the R9-R11 mechanism: each WT fragment feeds 4 MFMAs,
// 8 NT x-loads in flight per kk. acc = 128 regs (AGPR-backed on gfx950's
// unified file; R11 showed VGPR_Count=84 for 96 accs -> accs live in AGPRs).
// (256,2) = 256-VGPR cap: spill impossible; 32 independent MFMAs per
// b-load group supply ILP at the reduced 8-waves/CU occupancy.
__global__ __launch_bounds__(256, 2) void gemm_kernel(
        const float* __restrict__ x,
        const __bf16* __restrict__ WT,
        __bf16* __restrict__ h) {
    __shared__ __bf16 lsm[4][16][144];
    const int wave = threadIdx.x >> 6;
    const int lane = threadIdx.x & 63;
    const int qt = blockIdx.x * 4 + wave;
    if (qt >= N_QUADT) return;
    const int t0 = qt * 4, t1 = t0 + 1, t2 = t0 + 2, t3 = t0 + 3;
    const bool v1 = (t1 < N_TILES), v2 = (t2 < N_TILES), v3 = (t3 < N_TILES);
    const int m = lane & 15, quad = lane >> 4;
    const float* xp0 = x + (size_t)(t0 * 16 + m) * D + quad * 8;
    const float* xp1 = x + (size_t)((v1 ? t1 * 16 : 0) + m) * D + quad * 8;  // clamped if invalid
    const float* xp2 = x + (size_t)((v2 ? t2 * 16 : 0) + m) * D + quad * 8;
    const float* xp3 = x + (size_t)((v3 ? t3 * 16 : 0) + m) * D + quad * 8;

    f32x4 acc0[8], acc1[8], acc2[8], acc3[8];
#pragma unroll
    for (int ct = 0; ct < 8; ++ct) {
        acc0[ct] = (f32x4)(0.0f); acc1[ct] = (f32x4)(0.0f);
        acc2[ct] = (f32x4)(0.0f); acc3[ct] = (f32x4)(0.0f);
    }
#pragma unroll
    for (int kk = 0; kk < 4; ++kk) {
        f32x4 a00 = __builtin_nontemporal_load((const f32x4*)(xp0 + kk * 32));
        f32x4 a01 = __builtin_nontemporal_load((const f32x4*)(xp0 + kk * 32 + 4));
        f32x4 a10 = __builtin_nontemporal_load((const f32x4*)(xp1 + kk * 32));
        f32x4 a11 = __builtin_nontemporal_load((const f32x4*)(xp1 + kk * 32 + 4));
        f32x4 a20 = __builtin_nontemporal_load((const f32x4*)(xp2 + kk * 32));
        f32x4 a21 = __builtin_nontemporal_load((const f32x4*)(xp2 + kk * 32 + 4));
        f32x4 a30 = __builtin_nontemporal_load((const f32x4*)(xp3 + kk * 32));
        f32x4 a31 = __builtin_nontemporal_load((const f32x4*)(xp3 + kk * 32 + 4));
        bf16x8 a0, a1, a2, a3;
#pragma unroll
        for (int j = 0; j < 4; ++j) {
            a0[j] = (__bf16)a00[j]; a0[j + 4] = (__bf16)a01[j];
            a1[j] = (__bf16)a10[j]; a1[j + 4] = (__bf16)a11[j];
            a2[j] = (__bf16)a20[j]; a2[j + 4] = (__bf16)a21[j];
            a3[j] = (__bf16)a30[j]; a3[j + 4] = (__bf16)a31[j];
        }
#pragma unroll
        for (int ct = 0; ct < 8; ++ct) {
            bf16x8 b = *(const bf16x8*)(WT + (size_t)(ct * 16 + m) * D + kk * 32 + quad * 8);
            acc0[ct] = __builtin_amdgcn_mfma_f32_16x16x32_bf16(a0, b, acc0[ct], 0, 0, 0);
            acc1[ct] = __builtin_amdgcn_mfma_f32_16x16x32_bf16(a1, b, acc1[ct], 0, 0, 0);
            acc2[ct] = __builtin_amdgcn_mfma_f32_16x16x32_bf16(a2, b, acc2[ct], 0, 0, 0);
            acc3[ct] = __builtin_amdgcn_mfma_f32_16x16x32_bf16(a3, b, acc3[ct], 0, 0, 0);
        }
    }
    // epilogue through the wave-private lsm slice (in-wave LDS ordering is
    // handled by compiler lgkmcnt waits; no barrier needed)
#define EPI(ACC, T)                                                          \
    {                                                                        \
        _Pragma("unroll")                                                    \
        for (int ct = 0; ct < 8; ++ct)                                       \
            _Pragma("unroll")                                                \
            for (int r = 0; r < 4; ++r)                                      \
                lsm[wave][quad * 4 + r][ct * 16 + m] = (__bf16)ACC[ct][r];   \
        _Pragma("unroll")                                                    \
        for (int i = 0; i < 4; ++i) {                                        \
            int rl = i * 4 + quad;                                           \
            bf16x8 vv = *(const bf16x8*)&lsm[wave][rl][m * 8];               \
            *(bf16x8*)(h + (size_t)((T) * 16 + rl) * D + m * 8) = vv;        \
        }                                                                    \
    }
    EPI(acc0, t0)
    if (v1) EPI(acc1, t1)
    if (v2) EPI(acc2, t2)
    if (v3) EPI(acc3, t3)
#undef EPI
}

// ---- K3: scatterB — exact LDS counting sort + cooperative drain (R9-proven) ----
__global__ __launch_bounds__(1024, 8) void scatterB_kernel(
        const int* __restrict__ rows, const int* __restrict__ cols,
        const float* __restrict__ vals,
        int* __restrict__ bucketCnt, i32x2* __restrict__ svcA) {
    __shared__ i32x2 lbuf[SB_EDGES];   // 50000 B
    __shared__ int   lhist[NB];        // counts (preserved)
    __shared__ int   sstart[NB];       // exclusive starts
    __shared__ int   lcur[NB];         // scatter cursors, then g broadcast
    const int tid  = threadIdx.x;
    const int base = blockIdx.x * SB_EDGES;

    if (tid < NB) lhist[tid] = 0;
    __syncthreads();

    i32x2 r0, r1, r2, r3, r4, r5, r6;
    int   b0, b1, b2, b3, b4, b5, b6;
#define LOADREC(K, RK, BK)                                             \
    {                                                                  \
        int e = base + tid + (K) * 1024;                               \
        int rr = rows[e];                                              \
        BK = rr / RPB;                                                 \
        int local = rr - BK * RPB;                                     \
        RK[0] = (local << 17) | cols[e];                               \
        RK[1] = __float_as_int(vals[e]);                               \
        atomicAdd(&lhist[BK], 1);                                      \
    }
    LOADREC(0, r0, b0) LOADREC(1, r1, b1) LOADREC(2, r2, b2)
    LOADREC(3, r3, b3) LOADREC(4, r4, b4) LOADREC(5, r5, b5)
    if (tid < SB_EDGES - 6 * 1024) { LOADREC(6, r6, b6) }
#undef LOADREC
    __syncthreads();

    if (tid < 64) {
        const int bb = tid * 8;
        int run = 0;
#pragma unroll
        for (int j = 0; j < 8; ++j) run += lhist[bb + j];
        int s = run;
#pragma unroll
        for (int d = 1; d < 64; d <<= 1) {
            int t2 = __shfl_up(s, d, 64);
            if (tid >= d) s += t2;
        }
        int ex = s - run;
#pragma unroll
        for (int j = 0; j < 8; ++j) {
            sstart[bb + j] = ex;
            lcur[bb + j]   = ex;
            ex += lhist[bb + j];
        }
    }
    __syncthreads();

    lbuf[atomicAdd(&lcur[b0], 1)] = r0;
    lbuf[atomicAdd(&lcur[b1], 1)] = r1;
    lbuf[atomicAdd(&lcur[b2], 1)] = r2;
    lbuf[atomicAdd(&lcur[b3], 1)] = r3;
    lbuf[atomicAdd(&lcur[b4], 1)] = r4;
    lbuf[atomicAdd(&lcur[b5], 1)] = r5;
    if (tid < SB_EDGES - 6 * 1024) lbuf[atomicAdd(&lcur[b6], 1)] = r6;
    __syncthreads();

    if (tid < NB) {
        int n = lhist[tid];
        if (n > 0) lcur[tid] = atomicAdd(&bucketCnt[tid], n);   // reuse lcur as g
    }
    __syncthreads();

    {
        const int bkt  = tid >> 1;
        const int half = tid & 1;
        int n = lhist[bkt];
        if (n > 0) {
            int g = lcur[bkt];
            int s = sstart[bkt];
            i32x2* dst = svcA + (size_t)bkt * BCAP;
            for (int i = half; i < n; i += 2)
                if (g + i < BCAP) dst[g + i] = lbuf[s + i];
        }
    }
}

// ---- K4: fused local sort + segsum + relu (R1-proven, ~65us, untouched) ----
__device__ __forceinline__ f32x2 bf2f(unsigned u) {
    f32x2 r;
    r[0] = __int_as_float(u << 16);
    r[1] = __int_as_float(u & 0xffff0000u);
    return r;
}

__global__ __launch_bounds__(1024, 8) void sortsum_kernel(
        const __bf16* __restrict__ h, const int* __restrict__ bucketCnt,
        const i32x2* __restrict__ svcA, float* __restrict__ out) {
    __shared__ i32x2 lbuf[BCAP];     // 28 KB
    __shared__ int   lhist[256];
    __shared__ int   send[256];      // inclusive scan (row ends)
    __shared__ int   lcur[256];      // scatter cursors (row starts, mutated)
    const int b   = blockIdx.x;
    const int tid = threadIdx.x;
    const int n   = min(bucketCnt[b], BCAP);
    const i32x2* win = svcA + (size_t)b * BCAP;

    if (tid < 256) lhist[tid] = 0;
    __syncthreads();

    i32x2 rec0, rec1, rec2, rec3;
    const int i0 = tid, i1 = tid + 1024, i2 = tid + 2048, i3 = tid + 3072;
    if (i0 < n) { rec0 = win[i0]; atomicAdd(&lhist[((unsigned)rec0[0]) >> 17], 1); }
    if (i1 < n) { rec1 = win[i1]; atomicAdd(&lhist[((unsigned)rec1[0]) >> 17], 1); }
    if (i2 < n) { rec2 = win[i2]; atomicAdd(&lhist[((unsigned)rec2[0]) >> 17], 1); }
    if (i3 < n) { rec3 = win[i3]; atomicAdd(&lhist[((unsigned)rec3[0]) >> 17], 1); }
    __syncthreads();

    if (tid < 64) {
        int b0 = lhist[tid * 4 + 0], b1 = lhist[tid * 4 + 1];
        int b2 = lhist[tid * 4 + 2], b3 = lhist[tid * 4 + 3];
        int p0 = b0, p1 = p0 + b1, p2 = p1 + b2, p3 = p2 + b3;
        int s = p3;
#pragma unroll
        for (int d = 1; d < 64; d <<= 1) {
            int t2 = __shfl_up(s, d, 64);
            if (tid >= d) s += t2;
        }
        int ex = s - p3;
        send[tid * 4 + 0] = ex + p0;
        send[tid * 4 + 1] = ex + p1;
        send[tid * 4 + 2] = ex + p2;
        send[tid * 4 + 3] = ex + p3;
        lcur[tid * 4 + 0] = ex;
        lcur[tid * 4 + 1] = ex + p0;
        lcur[tid * 4 + 2] = ex + p1;
        lcur[tid * 4 + 3] = ex + p2;
    }
    __syncthreads();

    if (i0 < n) { int rl = ((unsigned)rec0[0]) >> 17; lbuf[atomicAdd(&lcur[rl], 1)] = rec0; }
    if (i1 < n) { int rl = ((unsigned)rec1[0]) >> 17; lbuf[atomicAdd(&lcur[rl], 1)] = rec1; }
    if (i2 < n) { int rl = ((unsigned)rec2[0]) >> 17; lbuf[atomicAdd(&lcur[rl], 1)] = rec2; }
    if (i3 < n) { int rl = ((unsigned)rec3[0]) >> 17; lbuf[atomicAdd(&lcur[rl], 1)] = rec3; }
    __syncthreads();

    const int wave = tid >> 6;
    const int lane = tid & 63;
    const char* hb = (const char*)h;
    const unsigned lo4 = (unsigned)lane * 4u;
    for (int rl = wave; rl < RPB; rl += 16) {
        int gr = b * RPB + rl;
        if (gr >= N_NODES) break;
        int s = rl ? send[rl - 1] : 0;
        int e = send[rl];

        f32x2 acc0 = (f32x2)(0.0f), acc1 = (f32x2)(0.0f);
        f32x2 acc2 = (f32x2)(0.0f), acc3 = (f32x2)(0.0f);
        int i = s;
        for (; i + 7 < e; i += 8) {
            i32x2 r0 = lbuf[i],     r1 = lbuf[i + 1], r2 = lbuf[i + 2], r3 = lbuf[i + 3];
            i32x2 r4 = lbuf[i + 4], r5 = lbuf[i + 5], r6 = lbuf[i + 6], r7 = lbuf[i + 7];
            unsigned o0 = (((unsigned)r0[0] & 0x1FFFFu) << 8) + lo4;
            unsigned o1 = (((unsigned)r1[0] & 0x1FFFFu) << 8) + lo4;
            unsigned o2 = (((unsigned)r2[0] & 0x1FFFFu) << 8) + lo4;
            unsigned o3 = (((unsigned)r3[0] & 0x1FFFFu) << 8) + lo4;
            unsigned o4 = (((unsigned)r4[0] & 0x1FFFFu) << 8) + lo4;
            unsigned o5 = (((unsigned)r5[0] & 0x1FFFFu) << 8) + lo4;
            unsigned o6 = (((unsigned)r6[0] & 0x1FFFFu) << 8) + lo4;
            unsigned o7 = (((unsigned)r7[0] & 0x1FFFFu) << 8) + lo4;
            unsigned u0 = *(const unsigned*)(hb + o0);
            unsigned u1 = *(const unsigned*)(hb + o1);
            unsigned u2 = *(const unsigned*)(hb + o2);
            unsigned u3 = *(const unsigned*)(hb + o3);
            unsigned u4 = *(const unsigned*)(hb + o4);
            unsigned u5 = *(const unsigned*)(hb + o5);
            unsigned u6 = *(const unsigned*)(hb + o6);
            unsigned u7 = *(const unsigned*)(hb + o7);
            acc0 += bf2f(u0) * __int_as_float(r0[1]);
            acc1 += bf2f(u1) * __int_as_float(r1[1]);
            acc2 += bf2f(u2) * __int_as_float(r2[1]);
            acc3 += bf2f(u3) * __int_as_float(r3[1]);
            acc0 += bf2f(u4) * __int_as_float(r4[1]);
            acc1 += bf2f(u5) * __int_as_float(r5[1]);
            acc2 += bf2f(u6) * __int_as_float(r6[1]);
            acc3 += bf2f(u7) * __int_as_float(r7[1]);
        }
        for (; i + 3 < e; i += 4) {
            i32x2 r0 = lbuf[i], r1 = lbuf[i + 1], r2 = lbuf[i + 2], r3 = lbuf[i + 3];
            unsigned o0 = (((unsigned)r0[0] & 0x1FFFFu) << 8) + lo4;
            unsigned o1 = (((unsigned)r1[0] & 0x1FFFFu) << 8) + lo4;
            unsigned o2 = (((unsigned)r2[0] & 0x1FFFFu) << 8) + lo4;
            unsigned o3 = (((unsigned)r3[0] & 0x1FFFFu) << 8) + lo4;
            unsigned u0 = *(const unsigned*)(hb + o0);
            unsigned u1 = *(const unsigned*)(hb + o1);
            unsigned u2 = *(const unsigned*)(hb + o2);
            unsigned u3 = *(const unsigned*)(hb + o3);
            acc0 += bf2f(u0) * __int_as_float(r0[1]);
            acc1 += bf2f(u1) * __int_as_float(r1[1]);
            acc2 += bf2f(u2) * __int_as_float(r2[1]);
            acc3 += bf2f(u3) * __int_as_float(r3[1]);
        }
        for (; i < e; ++i) {
            i32x2 r0 = lbuf[i];
            unsigned o0 = (((unsigned)r0[0] & 0x1FFFFu) << 8) + lo4;
            unsigned u0 = *(const unsigned*)(hb + o0);
            acc0 += bf2f(u0) * __int_as_float(r0[1]);
        }

        f32x2 t01 = acc0 + acc1, t23 = acc2 + acc3;
        f32x2 tt = t01 + t23;
        f32x2 o;
        o[0] = fmaxf(tt[0], 0.0f);
        o[1] = fmaxf(tt[1], 0.0f);
        __builtin_nontemporal_store(o, (f32x2*)(out + (size_t)gr * D + lane * 2));
    }
}

extern "C" void kernel_launch(void* const* d_in, const int* in_sizes, int n_in,
                              void* d_out, int out_size, void* d_ws, size_t ws_size,
                              hipStream_t stream) {
    const float* x    = (const float*)d_in[0];
    const float* w    = (const float*)d_in[1];
    const float* vals = (const float*)d_in[2];
    const int*   rows = (const int*)d_in[3];
    const int*   cols = (const int*)d_in[4];
    float*       out  = (float*)d_out;

    // ---- workspace (~40.3 MB) ----
    char* p = (char*)d_ws;
    __bf16* h         = (__bf16*)p;  p += (size_t)N_NODES * D * 2;          // 25.6 MB
    __bf16* WT        = (__bf16*)p;  p += (size_t)D * D * 2;                // 32 KB
    int*    bucketCnt = (int*)p;     p += 4096;                             // NB ints
    i32x2*  svcA      = (i32x2*)p;   p += (size_t)NB * BCAP * 8;            // 14.7 MB

    prep_kernel<<<64, 256, 0, stream>>>(w, WT, bucketCnt);
    gemm_kernel<<<(N_QUADT + 3) / 4, 256, 0, stream>>>(x, WT, h);
    scatterB_kernel<<<SB_BLKS, 1024, 0, stream>>>(rows, cols, vals, bucketCnt, svcA);
    sortsum_kernel<<<NB, 1024, 0, stream>>>(h, bucketCnt, svcA, out);
}